// Round 3
// baseline (114982.776 us; speedup 1.0000x reference)
//
#include <hip/hip_runtime.h>

#define NPER 512
#define CDIM 256
#define BG   64
#define NB   128
#define TPB  256
#define GW   8      // graphs per cluster
#define CW   16     // channels per member block
#define WST  258    // col-major weight stride (256 + 2): bank stride 2 -> free
#define AST  10     // k-major activation stride (8 graphs + 2 pad)
#define CAP  64
#define ESC  64     // poll retries before escaping to L2-point atomic reads

// Zero det slots + tagged exchange buffers (tags must be 0 so step-1 polls for
// tag 0 succeed immediately and stale tags from a previous replay can't alias).
__global__ void init_ws(unsigned long long* p, int n) {
    int i = blockIdx.x * blockDim.x + threadIdx.x;
    if (i < n) p[i] = 0ULL;
}

__device__ __forceinline__ float ld_sc(const float* p) {
    return __hip_atomic_load((const float*)p, __ATOMIC_RELAXED, __HIP_MEMORY_SCOPE_AGENT);
}
__device__ __forceinline__ void st_sc(float* p, float v) {
    __hip_atomic_store(p, v, __ATOMIC_RELAXED, __HIP_MEMORY_SCOPE_AGENT);
}

// One 8B store carries (value, tag) together: no fence / store-order assumption.
// fast=true: non-returning atomic swap -- executes AT the XCD-local L2
// coherence point, so same-XCD visibility is guaranteed independent of any L0
// write policy. Valid only when the whole cluster verifiably shares one XCD.
// fast=false: agent-scope store (LLC-homed), correct on any mapping.
__device__ __forceinline__ void st_tag(float* buf, int idx, float v, unsigned tg,
                                       bool fast) {
    unsigned long long u = ((unsigned long long)tg << 32) |
                           (unsigned long long)__float_as_uint(v);
    unsigned long long* p = (unsigned long long*)(buf + 2 * (size_t)idx);
    if (fast)
        asm volatile("global_atomic_swap_x2 %0, %1, off" :: "v"(p), "v"(u) : "memory");
    else
        __hip_atomic_store(p, u, __ATOMIC_RELAXED, __HIP_MEMORY_SCOPE_AGENT);
}

// Poll a cluster's tagged exchange buffer until all 2048 (value,tag) pairs
// carry `tg`. Detection and data arrive in the same round-trip.
// Single-buffer WAR safety: the step chain (hnew->z->agg->hnew) guarantees a
// producer writing step t has observed all step-t inputs, which implies every
// consumer finished its step t-1 reads of this buffer.
// Fast path: sc0 loads (L0-bypass reads of the XCD L2) for the first ESC
// retries; then escape to returning atomic add-0 reads, which execute AT the
// L2 and are immune to any L0 staleness -- guaranteed forward progress.
// A stale plain load can only show an old tag (tag+data move in one atomic
// 8B pair), so acceptance is always consistent. The per-retry vmcnt(0) +
// sched_barrier(0) is the guide-rule-18 fence for the inline-asm loads (and
// it also drains this thread's earlier hx/hold traffic -- see P1).
__device__ __forceinline__ void poll_tag(const float* buf, unsigned tg, int tid,
                                         float* vals, bool fast) {
    unsigned long long u[8];
    int ok = 0, tries = 0;
    do {
        if (!ok) {
            if (fast) {
                if (++tries <= ESC) {
                    #pragma unroll
                    for (int j = 0; j < 8; ++j) {
                        const unsigned long long* p =
                            (const unsigned long long*)(buf + 2 * (size_t)(j * TPB + tid));
                        asm volatile("global_load_dwordx2 %0, %1, off sc0"
                                     : "=v"(u[j]) : "v"(p));
                    }
                } else {
                    #pragma unroll
                    for (int j = 0; j < 8; ++j) {
                        unsigned long long* p =
                            (unsigned long long*)(buf + 2 * (size_t)(j * TPB + tid));
                        asm volatile("global_atomic_add_x2 %0, %1, %2, off sc0"
                                     : "=&v"(u[j]) : "v"(p), "v"(0ULL) : "memory");
                    }
                }
                asm volatile("s_waitcnt vmcnt(0)" ::: "memory");
                __builtin_amdgcn_sched_barrier(0);
            } else {
                #pragma unroll
                for (int j = 0; j < 8; ++j)
                    u[j] = __hip_atomic_load(
                        (const unsigned long long*)(buf + 2 * (size_t)(j * TPB + tid)),
                        __ATOMIC_RELAXED, __HIP_MEMORY_SCOPE_AGENT);
            }
            ok = 1;
            #pragma unroll
            for (int j = 0; j < 8; ++j) ok &= ((unsigned)(u[j] >> 32) == tg);
        }
    } while (!__syncthreads_and(ok));
    #pragma unroll
    for (int j = 0; j < 8; ++j) vals[j] = __uint_as_float((unsigned)(u[j] & 0xffffffffu));
}

__global__ __launch_bounds__(TPB, 1)
void gnn_fp32(const float* __restrict__ x,
              const float* __restrict__ W1g, const float* __restrict__ b1g,
              const float* __restrict__ W2g, const float* __restrict__ b2g,
              const float* __restrict__ wihg, const float* __restrict__ bihg,
              const float* __restrict__ whhg, const float* __restrict__ bhhg,
              const int* __restrict__ src_f, const int* __restrict__ gid_f,
              const float* __restrict__ msk_f,
              const int* __restrict__ src_b, const int* __restrict__ gid_b,
              const float* __restrict__ msk_b,
              int Kf, int Kb,
              float* __restrict__ hx,
              float* __restrict__ xh, float* __restrict__ xz,
              float* __restrict__ xa, float* __restrict__ ring,
              int* det)
{
    __shared__ float sh_w[128 * WST];    // col-major rows: 0-47 wih, 48-95 whh, 96-111 W1, 112-127 W2
    __shared__ float sh_act[256 * AST];
    __shared__ float sh_hold[256 * AST];
    __shared__ float sh_gi[GW * 48];
    __shared__ float sh_gh[GW * 48];
    __shared__ int   sh_list[GW * CAP];
    __shared__ int   sh_cnt[GW];
    __shared__ int   sh_det[16];
    __shared__ float sh_bih[48], sh_bhh[48], sh_b1[CW], sh_b2[CW];

    const int tid   = threadIdx.x;
    const int cl    = blockIdx.x & 7;
    const int mb    = blockIdx.x >> 3;
    const int gb    = cl * GW;
    const int cbase = mb * CW;

    float* xh_c = xh + (size_t)cl * GW * CDIM * 2;
    float* xz_c = xz + (size_t)cl * GW * CDIM * 2;
    float* xa_c = xa + (size_t)cl * GW * CDIM * 2;
    float* ring_blk = ring + (size_t)blockIdx.x * 64 * GW * CW;

    // ---- XCD-affinity detection: fast L2-local exchange iff all 16 cluster
    // members share one XCD (G16: never ASSUME the workgroup->XCD mapping).
    unsigned xcc;
    asm volatile("s_getreg_b32 %0, hwreg(HW_REG_XCC_ID)" : "=s"(xcc));
    const int mine = (int)(0x5A500000u | (xcc & 0xffffu));
    if (tid == 0)
        __hip_atomic_store(det + blockIdx.x, mine, __ATOMIC_RELAXED, __HIP_MEMORY_SCOPE_AGENT);
    if (tid < 16) {
        int v;
        do {
            v = __hip_atomic_load(det + cl + 8 * tid, __ATOMIC_RELAXED, __HIP_MEMORY_SCOPE_AGENT);
            if (!v) __builtin_amdgcn_s_sleep(1);
        } while (!v);
        sh_det[tid] = v;
    }

    // ---- stage weights col-major into LDS, once ----
    for (int e = tid; e < 128 * 256; e += TPB) {
        int r = e >> 8, k = e & 255;
        const float* sp; int grow;
        if (r < 48)       { sp = wihg; grow = (r >> 4) * CDIM + cbase + (r & 15); }
        else if (r < 96)  { sp = whhg; grow = ((r - 48) >> 4) * CDIM + cbase + ((r - 48) & 15); }
        else if (r < 112) { sp = W1g;  grow = cbase + (r - 96); }
        else              { sp = W2g;  grow = cbase + (r - 112); }
        sh_w[r * WST + k] = sp[(size_t)grow * CDIM + k];
    }
    if (tid < 48) {
        sh_bih[tid] = bihg[(tid >> 4) * CDIM + cbase + (tid & 15)];
        sh_bhh[tid] = bhhg[(tid >> 4) * CDIM + cbase + (tid & 15)];
    } else if (tid < 64) {
        sh_b1[tid - 48] = b1g[cbase + tid - 48];
        sh_b2[tid - 48] = b2g[cbase + tid - 48];
    }
    __syncthreads();

    int fastf = 1;
    #pragma unroll
    for (int m = 0; m < 16; ++m) fastf &= (sh_det[m] == mine);
    const bool fast = (fastf != 0);

    float keep0 = 0.f;
    const int cg = tid >> 4;
    const int cc = tid & 15;

    for (int pass = 0; pass < 2; ++pass) {
        const int* srcA   = pass ? src_b : src_f;
        const int* gidA   = pass ? gid_b : gid_f;
        const float* mskA = pass ? msk_b : msk_f;
        const int K = pass ? Kb : Kf;

        for (int s = 0; s < NPER; ++s) {
            const int node = pass ? (NPER - 1 - s) : s;
            const unsigned tg = (unsigned)(pass * NPER + s + 1);
            const bool has_prev = !(pass == 0 && s == 0);
            const int prev = (s > 0) ? (pass ? node + 1 : node - 1) : (NPER - 1);

            // ======= P1: deferred hx write; hold prefetch; poll hnew; W1 GEMM =======
            if (has_prev && tid < 128) {
                float* p = &hx[((size_t)(gb + cg) * NPER + prev) * CDIM + cbase + cc];
                if (fast) {
                    unsigned kb = __float_as_uint(keep0);
                    // L2-point write: visible to same-XCD atomic/sc0 readers.
                    asm volatile("global_atomic_swap %0, %1, off" :: "v"(p), "v"(kb) : "memory");
                } else {
                    st_sc(p, keep0);
                }
            }
            float holdv[8];
            if (pass == 1 && s > 0) {           // issue early: completes under the poll
                if (fast) {
                    #pragma unroll
                    for (int j = 0; j < 8; ++j) {
                        float* p = (float*)&hx[((size_t)(gb + j) * NPER + node) * CDIM + tid];
                        // L2-point read (add 0, returning); poll's vmcnt(0)+
                        // sched_barrier fences before use.
                        asm volatile("global_atomic_add %0, %1, %2, off sc0"
                                     : "=&v"(holdv[j]) : "v"(p), "v"(0) : "memory");
                    }
                } else {
                    #pragma unroll
                    for (int j = 0; j < 8; ++j)
                        holdv[j] = ld_sc(&hx[((size_t)(gb + j) * NPER + node) * CDIM + tid]);
                }
            }
            if (tid < GW) sh_cnt[tid] = 0;

            float hv[8];
            poll_tag(xh_c, tg - 1, tid, hv, fast);  // tag 0 at (pass0,s0): zeros, unused downstream
            #pragma unroll
            for (int j = 0; j < 8; ++j) sh_act[tid * AST + j] = hv[j];
            if (pass == 0) {                    // h_old = x (read-only: cached loads)
                int sg = tid & 7, skb = (tid >> 3) << 3;
                const float* op = x + ((size_t)(gb + sg) * NPER + node) * CDIM + skb;
                float4 h0 = *(const float4*)op, h1 = *(const float4*)(op + 4);
                float* d = &sh_hold[skb * AST + sg];
                d[0] = h0.x; d[AST] = h0.y; d[2*AST] = h0.z; d[3*AST] = h0.w;
                d[4*AST] = h1.x; d[5*AST] = h1.y; d[6*AST] = h1.z; d[7*AST] = h1.w;
            } else if (s == 0) {                // h_old(node 511) == hnew from fwd end
                #pragma unroll
                for (int j = 0; j < 8; ++j) sh_hold[tid * AST + j] = hv[j];
            } else {
                #pragma unroll
                for (int j = 0; j < 8; ++j) sh_hold[tid * AST + j] = holdv[j];
            }
            __syncthreads();

            {   // W1 GEMM (rows 96..111) -> z tagged
                const int tl = tid >> 5, ks = tid & 31;
                const float* wr0 = &sh_w[(96 + tl * 2) * WST];
                const float* wr1 = wr0 + WST;
                float acc0[8] = {}, acc1[8] = {};
                #pragma unroll
                for (int j = 0; j < 8; ++j) {
                    int k = ks + j * 32;
                    float w0 = wr0[k], w1 = wr1[k];
                    const float* ap = &sh_act[k * AST];
                    #pragma unroll
                    for (int g = 0; g < 8; ++g) {
                        float a = ap[g];
                        acc0[g] += w0 * a; acc1[g] += w1 * a;
                    }
                }
                #pragma unroll
                for (int m = 1; m < 32; m <<= 1)
                    #pragma unroll
                    for (int g = 0; g < 8; ++g) {
                        acc0[g] += __shfl_xor(acc0[g], m, 64);
                        acc1[g] += __shfl_xor(acc1[g], m, 64);
                    }
                if (ks < 8) {
                    int g = ks, c0 = tl * 2;
                    float v0 = acc0[g] + sh_b1[c0];
                    float v1 = acc1[g] + sh_b1[c0 + 1];
                    st_tag(xz_c, g * CDIM + cbase + c0,     v0 > 0.f ? v0 : 0.f, tg, fast);
                    st_tag(xz_c, g * CDIM + cbase + c0 + 1, v1 > 0.f ? v1 : 0.f, tg, fast);
                }
            }
            // edge filter here: covers z's flight before the P2 poll
            for (int e = tid; e < K; e += TPB) {
                size_t off = (size_t)s * K + e;
                if (mskA[off] != 0.f) {
                    int g = gidA[off] - gb;
                    if ((unsigned)g < GW) {
                        int p = atomicAdd(&sh_cnt[g], 1);
                        if (p < CAP) sh_list[g * CAP + p] = srcA[off] & 63;
                    }
                }
            }

            // ======= P2: poll z; ring = relu(W2 z); aggregate -> agg tagged =======
            float zv[8];
            poll_tag(xz_c, tg, tid, zv, fast);
            #pragma unroll
            for (int j = 0; j < 8; ++j) sh_act[tid * AST + j] = zv[j];
            __syncthreads();

            {   // W2 GEMM (rows 112..127) -> ring[prev & 63] (block-private, cached)
                const int tl = tid >> 5, ks = tid & 31;
                const float* wr0 = &sh_w[(112 + tl * 2) * WST];
                const float* wr1 = wr0 + WST;
                float acc0[8] = {}, acc1[8] = {};
                #pragma unroll
                for (int j = 0; j < 8; ++j) {
                    int k = ks + j * 32;
                    float w0 = wr0[k], w1 = wr1[k];
                    const float* ap = &sh_act[k * AST];
                    #pragma unroll
                    for (int g = 0; g < 8; ++g) {
                        float a = ap[g];
                        acc0[g] += w0 * a; acc1[g] += w1 * a;
                    }
                }
                #pragma unroll
                for (int m = 1; m < 32; m <<= 1)
                    #pragma unroll
                    for (int g = 0; g < 8; ++g) {
                        acc0[g] += __shfl_xor(acc0[g], m, 64);
                        acc1[g] += __shfl_xor(acc1[g], m, 64);
                    }
                if (ks < 8) {
                    int g = ks, c0 = tl * 2, slot = prev & 63;
                    float v0 = acc0[g] + sh_b2[c0];
                    float v1 = acc1[g] + sh_b2[c0 + 1];
                    ring_blk[(slot * GW + g) * CW + c0]     = v0 > 0.f ? v0 : 0.f;
                    ring_blk[(slot * GW + g) * CW + c0 + 1] = v1 > 0.f ? v1 : 0.f;
                }
            }
            __syncthreads();
            if (tid < 128) {
                int n = sh_cnt[cg]; if (n > CAP) n = CAP;
                float a = 0.f;
                for (int i = 0; i < n; ++i)
                    a += ring_blk[(sh_list[cg * CAP + i] * GW + cg) * CW + cc];
                st_tag(xa_c, cg * CDIM + cbase + cc, a, tg, fast);
            }

            // ======= P3: gh GEMM (covers agg flight); poll agg; gi GEMM; gates =======
            if (tid < 192) {  // gh GEMM (rows 48..95) -> sh_gh
                const int tl = tid >> 4, ks = tid & 15;
                const float* wr = &sh_w[(48 + tl * 4) * WST];
                float acc[4][8] = {};
                #pragma unroll 4
                for (int j = 0; j < 16; ++j) {
                    int k = ks + j * 16;
                    float w0 = wr[k], w1 = wr[WST + k], w2 = wr[2 * WST + k], w3 = wr[3 * WST + k];
                    const float* ap = &sh_hold[k * AST];
                    #pragma unroll
                    for (int g = 0; g < 8; ++g) {
                        float a = ap[g];
                        acc[0][g] += w0 * a; acc[1][g] += w1 * a;
                        acc[2][g] += w2 * a; acc[3][g] += w3 * a;
                    }
                }
                #pragma unroll
                for (int m = 1; m < 16; m <<= 1)
                    #pragma unroll
                    for (int r = 0; r < 4; ++r)
                        #pragma unroll
                        for (int g = 0; g < 8; ++g)
                            acc[r][g] += __shfl_xor(acc[r][g], m, 64);
                if (ks < 8) {
                    int g = ks;
                    #pragma unroll
                    for (int r = 0; r < 4; ++r)
                        sh_gh[g * 48 + tl * 4 + r] = acc[r][g] + sh_bhh[tl * 4 + r];
                }
            }
            float av[8];
            poll_tag(xa_c, tg, tid, av, fast);
            #pragma unroll
            for (int j = 0; j < 8; ++j) sh_act[tid * AST + j] = av[j];
            __syncthreads();
            if (tid < 192) {  // gi GEMM (rows 0..47) -> sh_gi
                const int tl = tid >> 4, ks = tid & 15;
                const float* wr = &sh_w[(tl * 4) * WST];
                float acc[4][8] = {};
                #pragma unroll 4
                for (int j = 0; j < 16; ++j) {
                    int k = ks + j * 16;
                    float w0 = wr[k], w1 = wr[WST + k], w2 = wr[2 * WST + k], w3 = wr[3 * WST + k];
                    const float* ap = &sh_act[k * AST];
                    #pragma unroll
                    for (int g = 0; g < 8; ++g) {
                        float a = ap[g];
                        acc[0][g] += w0 * a; acc[1][g] += w1 * a;
                        acc[2][g] += w2 * a; acc[3][g] += w3 * a;
                    }
                }
                #pragma unroll
                for (int m = 1; m < 16; m <<= 1)
                    #pragma unroll
                    for (int r = 0; r < 4; ++r)
                        #pragma unroll
                        for (int g = 0; g < 8; ++g)
                            acc[r][g] += __shfl_xor(acc[r][g], m, 64);
                if (ks < 8) {
                    int g = ks;
                    #pragma unroll
                    for (int r = 0; r < 4; ++r)
                        sh_gi[g * 48 + tl * 4 + r] = acc[r][g] + sh_bih[tl * 4 + r];
                }
            }
            __syncthreads();
            if (tid < 128) {
                float ir = sh_gi[cg * 48 + cc], iz = sh_gi[cg * 48 + 16 + cc], in_ = sh_gi[cg * 48 + 32 + cc];
                float hr = sh_gh[cg * 48 + cc], hz = sh_gh[cg * 48 + 16 + cc], hn  = sh_gh[cg * 48 + 32 + cc];
                float hold = sh_hold[(cbase + cc) * AST + cg];
                float r  = 1.f / (1.f + expf(-(ir + hr)));
                float z_ = 1.f / (1.f + expf(-(iz + hz)));
                float nn = tanhf(in_ + r * hn);
                keep0 = (1.f - z_) * nn + z_ * hold;
                // pass0->pass1 hx handoff: drain our hx writes (atomic swaps are
                // vmcnt-tracked) before the tag that releases pass 1.
                if (pass == 0 && s == NPER - 1)
                    asm volatile("s_waitcnt vmcnt(0)" ::: "memory");
                st_tag(xh_c, cg * CDIM + cbase + cc, keep0, tg, fast);
            }
        }
    }
    if (tid < 128)
        st_sc(&hx[((size_t)(gb + cg) * NPER + 0) * CDIM + cbase + cc], keep0);
}

// ---------------- fallback (round-1 structure, known-correct) ----------------
__global__ __launch_bounds__(512)
void gnn_fallback(const float* __restrict__ x,
                  const float* __restrict__ W1, const float* __restrict__ b1,
                  const float* __restrict__ W2, const float* __restrict__ b2,
                  const float* __restrict__ w_ih, const float* __restrict__ b_ih,
                  const float* __restrict__ w_hh, const float* __restrict__ b_hh,
                  const int* __restrict__ src_f, const int* __restrict__ gid_f,
                  const float* __restrict__ msk_f,
                  const int* __restrict__ src_b, const int* __restrict__ gid_b,
                  const float* __restrict__ msk_b,
                  int Kf, int Kb, float* __restrict__ hx)
{
    const int b = blockIdx.x, t = threadIdx.x;
    __shared__ float sh_ring[64 * CDIM];
    __shared__ float sh_agg[CDIM], sh_hold[CDIM], sh_hnew[CDIM], sh_h1[CDIM];
    __shared__ float sh_gi[3 * CDIM], sh_gh[3 * CDIM];
    __shared__ int   sh_list[256];
    __shared__ int   sh_cnt;
    const size_t base = (size_t)b * NPER * CDIM;
    {
        const float4* x4 = (const float4*)(x + base);
        float4* h4 = (float4*)(hx + base);
        for (int i = t; i < NPER * CDIM / 4; i += 512) h4[i] = x4[i];
    }
    if (t == 0) sh_cnt = 0;
    __syncthreads();
    for (int pass = 0; pass < 2; ++pass) {
        const int* srcA = pass ? src_b : src_f;
        const int* gidA = pass ? gid_b : gid_f;
        const float* mskA = pass ? msk_b : msk_f;
        const int K = pass ? Kb : Kf;
        for (int step = 0; step < NPER; ++step) {
            const int node = pass ? (NPER - 1 - step) : step;
            if (t < CDIM / 4)
                ((float4*)sh_hold)[t] = ((const float4*)(hx + base + (size_t)node * CDIM))[t];
            for (int k = t; k < K; k += 512) {
                size_t off = (size_t)step * K + k;
                if (mskA[off] != 0.f && gidA[off] == b) {
                    int p = atomicAdd(&sh_cnt, 1);
                    if (p < 256) sh_list[p] = srcA[off] & 63;
                }
            }
            __syncthreads();
            int cnt = sh_cnt; if (cnt > 256) cnt = 256;
            if (t < CDIM) {
                float a = 0.f;
                for (int e = 0; e < cnt; ++e) a += sh_ring[sh_list[e] * CDIM + t];
                sh_agg[t] = a;
            }
            __syncthreads();
            #pragma unroll
            for (int d = 0; d < 3; ++d) {
                const int idx = t + d * 512;
                const float *wrow, *inv; float bias; float* outp;
                if (idx < 3 * CDIM) { wrow = w_ih + (size_t)idx * CDIM; inv = sh_agg; bias = b_ih[idx]; outp = &sh_gi[idx]; }
                else { int r = idx - 3 * CDIM; wrow = w_hh + (size_t)r * CDIM; inv = sh_hold; bias = b_hh[r]; outp = &sh_gh[r]; }
                float acc = 0.f;
                const float4* w4 = (const float4*)wrow; const float4* i4 = (const float4*)inv;
                #pragma unroll 8
                for (int j = 0; j < CDIM / 4; ++j) {
                    float4 w = w4[j], v = i4[j];
                    acc += w.x * v.x + w.y * v.y + w.z * v.z + w.w * v.w;
                }
                *outp = acc + bias;
            }
            __syncthreads();
            if (t < CDIM) {
                float ir = sh_gi[t], iz = sh_gi[t + CDIM], in_ = sh_gi[t + 2 * CDIM];
                float hr = sh_gh[t], hz = sh_gh[t + CDIM], hn = sh_gh[t + 2 * CDIM];
                float r = 1.f / (1.f + expf(-(ir + hr)));
                float z = 1.f / (1.f + expf(-(iz + hz)));
                float n = tanhf(in_ + r * hn);
                float hv = (1.f - z) * n + z * sh_hold[t];
                sh_hnew[t] = hv;
                hx[base + (size_t)node * CDIM + t] = hv;
            }
            if (t == 511) sh_cnt = 0;
            __syncthreads();
            if (t < CDIM) {
                const float4* w4 = (const float4*)(W1 + (size_t)t * CDIM);
                const float4* i4 = (const float4*)sh_hnew;
                float acc = 0.f;
                #pragma unroll 8
                for (int j = 0; j < CDIM / 4; ++j) {
                    float4 w = w4[j], v = i4[j];
                    acc += w.x * v.x + w.y * v.y + w.z * v.z + w.w * v.w;
                }
                acc += b1[t];
                sh_h1[t] = acc > 0.f ? acc : 0.f;
            }
            __syncthreads();
            if (t < CDIM) {
                const float4* w4 = (const float4*)(W2 + (size_t)t * CDIM);
                const float4* i4 = (const float4*)sh_h1;
                float acc = 0.f;
                #pragma unroll 8
                for (int j = 0; j < CDIM / 4; ++j) {
                    float4 w = w4[j], v = i4[j];
                    acc += w.x * v.x + w.y * v.y + w.z * v.z + w.w * v.w;
                }
                acc += b2[t];
                sh_ring[(node & 63) * CDIM + t] = acc > 0.f ? acc : 0.f;
            }
            __syncthreads();
        }
    }
}

extern "C" void kernel_launch(void* const* d_in, const int* in_sizes, int n_in,
                              void* d_out, int out_size, void* d_ws, size_t ws_size,
                              hipStream_t stream) {
    const float* x    = (const float*)d_in[0];
    const float* W1   = (const float*)d_in[1];
    const float* b1   = (const float*)d_in[2];
    const float* W2   = (const float*)d_in[3];
    const float* b2   = (const float*)d_in[4];
    const float* w_ih = (const float*)d_in[5];
    const float* b_ih = (const float*)d_in[6];
    const float* w_hh = (const float*)d_in[7];
    const float* b_hh = (const float*)d_in[8];
    const int*   src_f = (const int*)d_in[9];
    const int*   gid_f = (const int*)d_in[10];
    const float* msk_f = (const float*)d_in[11];
    const int*   src_b = (const int*)d_in[12];
    const int*   gid_b = (const int*)d_in[13];
    const float* msk_b = (const float*)d_in[14];

    const int Kf = in_sizes[9]  / NPER;
    const int Kb = in_sizes[12] / NPER;
    float* hx = (float*)d_out;

    char* ws = (char*)d_ws;
    // ws layout: [0,4096) det slots (128 ints used) | 3 tagged exchange
    // buffers (64 graphs x 256 ch x 8B each) | ring
    const size_t need = 4096 + 3 * (size_t)BG * CDIM * 8 + (size_t)NB * 64 * GW * CW * 4;
    if (ws_size >= need) {
        int*   det  = (int*)ws;
        float* xh   = (float*)(ws + 4096);
        float* xz   = xh + (size_t)BG * CDIM * 2;
        float* xa   = xz + (size_t)BG * CDIM * 2;
        float* ring = xa + (size_t)BG * CDIM * 2;
        // zero det (512 u64) + 3*64*256 = 49152 u64 tag pairs => 49664 u64
        init_ws<<<196, 256, 0, stream>>>((unsigned long long*)ws, 512 + 3 * BG * CDIM);
        gnn_fp32<<<NB, TPB, 0, stream>>>(
            x, W1, b1, W2, b2, w_ih, b_ih, w_hh, b_hh,
            src_f, gid_f, msk_f, src_b, gid_b, msk_b,
            Kf, Kb, hx, xh, xz, xa, ring, det);
    } else {
        gnn_fallback<<<BG, 512, 0, stream>>>(
            x, W1, b1, W2, b2, w_ih, b_ih, w_hh, b_hh,
            src_f, gid_f, msk_f, src_b, gid_b, msk_b,
            Kf, Kb, hx);
    }
}

// Round 4
// 38697.095 us; speedup vs baseline: 2.9714x; 2.9714x over previous
//
#include <hip/hip_runtime.h>

#define NPER 512
#define CDIM 256
#define BG   64
#define NB   128
#define TPB  256
#define GW   8      // graphs per cluster
#define CW   16     // channels per member block
#define WST  258    // col-major weight stride (256 + 2): bank stride 2 -> free
#define AST  10     // k-major activation stride (8 graphs + 2 pad)
#define CAP  64
#define ESC  16     // fast-poll retries before escaping to the safe (agent) copy

// Zero det slots + tagged exchange buffers (tags must be 0 so step-1 polls for
// tag 0 succeed immediately and stale tags from a previous replay can't alias).
__global__ void init_ws(unsigned long long* p, int n) {
    int i = blockIdx.x * blockDim.x + threadIdx.x;
    if (i < n) p[i] = 0ULL;
}

__device__ __forceinline__ float ld_sc(const float* p) {
    return __hip_atomic_load((const float*)p, __ATOMIC_RELAXED, __HIP_MEMORY_SCOPE_AGENT);
}
__device__ __forceinline__ void st_sc(float* p, float v) {
    __hip_atomic_store(p, v, __ATOMIC_RELAXED, __HIP_MEMORY_SCOPE_AGENT);
}

// Dual-publish: one 8B pair carries (value, tag) together -- no fence or
// store-order assumption anywhere.
//  - safe copy: agent-scope store (LLC-homed). Always written; on any
//    workgroup->XCD mapping this alone is the proven round-1 protocol.
//  - fast copy (fast=true only): plain dwordx2 store. vL1 is write-through,
//    so it lands in the XCD-local L2, readable by same-XCD members at L2
//    latency. Valid only because cluster co-residency on one XCD is VERIFIED.
__device__ __forceinline__ void st_tag(float* fb, float* sb, int idx, float v,
                                       unsigned tg, bool fast) {
    unsigned long long u = ((unsigned long long)tg << 32) |
                           (unsigned long long)__float_as_uint(v);
    if (fast) {
        unsigned long long* pf = (unsigned long long*)(fb + 2 * (size_t)idx);
        asm volatile("global_store_dwordx2 %0, %1, off" :: "v"(pf), "v"(u) : "memory");
    }
    __hip_atomic_store((unsigned long long*)(sb + 2 * (size_t)idx), u,
                       __ATOMIC_RELAXED, __HIP_MEMORY_SCOPE_AGENT);
}

// Poll until all 2048 (value,tag) pairs carry `tg`.
// Fast mode, first ESC tries: `buffer_inv sc0` (invalidate the CU's vL1 --
// the round-2/3 lesson: a polling loop's own first stale read parks the line
// in L0 and plain/sc0 re-reads hit it forever) + plain loads -> XCD-L2 hit.
// After ESC tries: permanently escape to agent-scope loads of the SAFE copy,
// which was published with sc1 and is guaranteed eventually visible ->
// bounded worst case = round-1 behavior, no hang, no atomic storm.
// vmcnt(0)+sched_barrier(0) per retry: rule-18 fence for the inline-asm loads
// (also drains this thread's earlier hx/hold traffic -- see P1).
// Single-buffer WAR safety: write/read cadence of both copies is identical to
// round 1 (step chain hnew->z->agg->hnew), so the round-1 argument holds.
__device__ __forceinline__ void poll_tag(const float* fb, const float* sb,
                                         unsigned tg, int tid, float* vals,
                                         bool fast) {
    unsigned long long u[8];
    int ok = 0, tries = 0;
    do {
        if (!ok) {
            if (fast && ++tries <= ESC) {
                asm volatile("buffer_inv sc0" ::: "memory");
                #pragma unroll
                for (int j = 0; j < 8; ++j) {
                    const unsigned long long* p =
                        (const unsigned long long*)(fb + 2 * (size_t)(j * TPB + tid));
                    asm volatile("global_load_dwordx2 %0, %1, off"
                                 : "=v"(u[j]) : "v"(p));
                }
                asm volatile("s_waitcnt vmcnt(0)" ::: "memory");
                __builtin_amdgcn_sched_barrier(0);
            } else {
                #pragma unroll
                for (int j = 0; j < 8; ++j)
                    u[j] = __hip_atomic_load(
                        (const unsigned long long*)(sb + 2 * (size_t)(j * TPB + tid)),
                        __ATOMIC_RELAXED, __HIP_MEMORY_SCOPE_AGENT);
            }
            ok = 1;
            #pragma unroll
            for (int j = 0; j < 8; ++j) ok &= ((unsigned)(u[j] >> 32) == tg);
        }
    } while (!__syncthreads_and(ok));
    #pragma unroll
    for (int j = 0; j < 8; ++j) vals[j] = __uint_as_float((unsigned)(u[j] & 0xffffffffu));
}

__global__ __launch_bounds__(TPB, 1)
void gnn_fp32(const float* __restrict__ x,
              const float* __restrict__ W1g, const float* __restrict__ b1g,
              const float* __restrict__ W2g, const float* __restrict__ b2g,
              const float* __restrict__ wihg, const float* __restrict__ bihg,
              const float* __restrict__ whhg, const float* __restrict__ bhhg,
              const int* __restrict__ src_f, const int* __restrict__ gid_f,
              const float* __restrict__ msk_f,
              const int* __restrict__ src_b, const int* __restrict__ gid_b,
              const float* __restrict__ msk_b,
              int Kf, int Kb,
              float* __restrict__ hx,
              float* __restrict__ xhf, float* __restrict__ xhs,
              float* __restrict__ xzf, float* __restrict__ xzs,
              float* __restrict__ xaf, float* __restrict__ xas,
              float* __restrict__ ring, int* det)
{
    __shared__ float sh_w[128 * WST];    // col-major rows: 0-47 wih, 48-95 whh, 96-111 W1, 112-127 W2
    __shared__ float sh_act[256 * AST];
    __shared__ float sh_hold[256 * AST];
    __shared__ float sh_gi[GW * 48];
    __shared__ float sh_gh[GW * 48];
    __shared__ int   sh_list[GW * CAP];
    __shared__ int   sh_cnt[GW];
    __shared__ int   sh_det[16];
    __shared__ float sh_bih[48], sh_bhh[48], sh_b1[CW], sh_b2[CW];

    const int tid   = threadIdx.x;
    const int cl    = blockIdx.x & 7;
    const int mb    = blockIdx.x >> 3;
    const int gb    = cl * GW;
    const int cbase = mb * CW;

    const size_t coff = (size_t)cl * GW * CDIM * 2;
    float* xhf_c = xhf + coff;  float* xhs_c = xhs + coff;
    float* xzf_c = xzf + coff;  float* xzs_c = xzs + coff;
    float* xaf_c = xaf + coff;  float* xas_c = xas + coff;
    float* ring_blk = ring + (size_t)blockIdx.x * 64 * GW * CW;

    // ---- XCD-affinity detection: fast L2-local exchange iff all 16 cluster
    // members share one XCD (G16: never ASSUME the workgroup->XCD mapping).
    unsigned xcc;
    asm volatile("s_getreg_b32 %0, hwreg(HW_REG_XCC_ID)" : "=s"(xcc));
    const int mine = (int)(0x5A500000u | (xcc & 0xffffu));
    if (tid == 0)
        __hip_atomic_store(det + blockIdx.x, mine, __ATOMIC_RELAXED, __HIP_MEMORY_SCOPE_AGENT);
    if (tid < 16) {
        int v;
        do {
            v = __hip_atomic_load(det + cl + 8 * tid, __ATOMIC_RELAXED, __HIP_MEMORY_SCOPE_AGENT);
            if (!v) __builtin_amdgcn_s_sleep(1);
        } while (!v);
        sh_det[tid] = v;
    }

    // ---- stage weights col-major into LDS, once ----
    for (int e = tid; e < 128 * 256; e += TPB) {
        int r = e >> 8, k = e & 255;
        const float* sp; int grow;
        if (r < 48)       { sp = wihg; grow = (r >> 4) * CDIM + cbase + (r & 15); }
        else if (r < 96)  { sp = whhg; grow = ((r - 48) >> 4) * CDIM + cbase + ((r - 48) & 15); }
        else if (r < 112) { sp = W1g;  grow = cbase + (r - 96); }
        else              { sp = W2g;  grow = cbase + (r - 112); }
        sh_w[r * WST + k] = sp[(size_t)grow * CDIM + k];
    }
    if (tid < 48) {
        sh_bih[tid] = bihg[(tid >> 4) * CDIM + cbase + (tid & 15)];
        sh_bhh[tid] = bhhg[(tid >> 4) * CDIM + cbase + (tid & 15)];
    } else if (tid < 64) {
        sh_b1[tid - 48] = b1g[cbase + tid - 48];
        sh_b2[tid - 48] = b2g[cbase + tid - 48];
    }
    __syncthreads();

    int fastf = 1;
    #pragma unroll
    for (int m = 0; m < 16; ++m) fastf &= (sh_det[m] == mine);
    const bool fast = (fastf != 0);

    float keep0 = 0.f;
    const int cg = tid >> 4;
    const int cc = tid & 15;

    for (int pass = 0; pass < 2; ++pass) {
        const int* srcA   = pass ? src_b : src_f;
        const int* gidA   = pass ? gid_b : gid_f;
        const float* mskA = pass ? msk_b : msk_f;
        const int K = pass ? Kb : Kf;

        for (int s = 0; s < NPER; ++s) {
            const int node = pass ? (NPER - 1 - s) : s;
            const unsigned tg = (unsigned)(pass * NPER + s + 1);
            const bool has_prev = !(pass == 0 && s == 0);
            const int prev = (s > 0) ? (pass ? node + 1 : node - 1) : (NPER - 1);

            // ======= P1: deferred hx write; hold prefetch; poll hnew; W1 GEMM =======
            if (has_prev && tid < 128)
                st_sc(&hx[((size_t)(gb + cg) * NPER + prev) * CDIM + cbase + cc], keep0);
            float holdv[8];
            if (pass == 1 && s > 0) {           // issue early: completes under the poll
                #pragma unroll
                for (int j = 0; j < 8; ++j)
                    holdv[j] = ld_sc(&hx[((size_t)(gb + j) * NPER + node) * CDIM + tid]);
            }
            if (tid < GW) sh_cnt[tid] = 0;

            float hv[8];
            poll_tag(xhf_c, xhs_c, tg - 1, tid, hv, fast);  // tag 0 at (pass0,s0): zeros, unused downstream
            #pragma unroll
            for (int j = 0; j < 8; ++j) sh_act[tid * AST + j] = hv[j];
            if (pass == 0) {                    // h_old = x (read-only: cached loads)
                int sg = tid & 7, skb = (tid >> 3) << 3;
                const float* op = x + ((size_t)(gb + sg) * NPER + node) * CDIM + skb;
                float4 h0 = *(const float4*)op, h1 = *(const float4*)(op + 4);
                float* d = &sh_hold[skb * AST + sg];
                d[0] = h0.x; d[AST] = h0.y; d[2*AST] = h0.z; d[3*AST] = h0.w;
                d[4*AST] = h1.x; d[5*AST] = h1.y; d[6*AST] = h1.z; d[7*AST] = h1.w;
            } else if (s == 0) {                // h_old(node 511) == hnew from fwd end
                #pragma unroll
                for (int j = 0; j < 8; ++j) sh_hold[tid * AST + j] = hv[j];
            } else {
                #pragma unroll
                for (int j = 0; j < 8; ++j) sh_hold[tid * AST + j] = holdv[j];
            }
            __syncthreads();

            {   // W1 GEMM (rows 96..111) -> z tagged
                const int tl = tid >> 5, ks = tid & 31;
                const float* wr0 = &sh_w[(96 + tl * 2) * WST];
                const float* wr1 = wr0 + WST;
                float acc0[8] = {}, acc1[8] = {};
                #pragma unroll
                for (int j = 0; j < 8; ++j) {
                    int k = ks + j * 32;
                    float w0 = wr0[k], w1 = wr1[k];
                    const float* ap = &sh_act[k * AST];
                    #pragma unroll
                    for (int g = 0; g < 8; ++g) {
                        float a = ap[g];
                        acc0[g] += w0 * a; acc1[g] += w1 * a;
                    }
                }
                #pragma unroll
                for (int m = 1; m < 32; m <<= 1)
                    #pragma unroll
                    for (int g = 0; g < 8; ++g) {
                        acc0[g] += __shfl_xor(acc0[g], m, 64);
                        acc1[g] += __shfl_xor(acc1[g], m, 64);
                    }
                if (ks < 8) {
                    int g = ks, c0 = tl * 2;
                    float v0 = acc0[g] + sh_b1[c0];
                    float v1 = acc1[g] + sh_b1[c0 + 1];
                    st_tag(xzf_c, xzs_c, g * CDIM + cbase + c0,     v0 > 0.f ? v0 : 0.f, tg, fast);
                    st_tag(xzf_c, xzs_c, g * CDIM + cbase + c0 + 1, v1 > 0.f ? v1 : 0.f, tg, fast);
                }
            }
            // edge filter here: covers z's flight before the P2 poll
            for (int e = tid; e < K; e += TPB) {
                size_t off = (size_t)s * K + e;
                if (mskA[off] != 0.f) {
                    int g = gidA[off] - gb;
                    if ((unsigned)g < GW) {
                        int p = atomicAdd(&sh_cnt[g], 1);
                        if (p < CAP) sh_list[g * CAP + p] = srcA[off] & 63;
                    }
                }
            }

            // ======= P2: poll z; ring = relu(W2 z); aggregate -> agg tagged =======
            float zv[8];
            poll_tag(xzf_c, xzs_c, tg, tid, zv, fast);
            #pragma unroll
            for (int j = 0; j < 8; ++j) sh_act[tid * AST + j] = zv[j];
            __syncthreads();

            {   // W2 GEMM (rows 112..127) -> ring[prev & 63] (block-private, cached)
                const int tl = tid >> 5, ks = tid & 31;
                const float* wr0 = &sh_w[(112 + tl * 2) * WST];
                const float* wr1 = wr0 + WST;
                float acc0[8] = {}, acc1[8] = {};
                #pragma unroll
                for (int j = 0; j < 8; ++j) {
                    int k = ks + j * 32;
                    float w0 = wr0[k], w1 = wr1[k];
                    const float* ap = &sh_act[k * AST];
                    #pragma unroll
                    for (int g = 0; g < 8; ++g) {
                        float a = ap[g];
                        acc0[g] += w0 * a; acc1[g] += w1 * a;
                    }
                }
                #pragma unroll
                for (int m = 1; m < 32; m <<= 1)
                    #pragma unroll
                    for (int g = 0; g < 8; ++g) {
                        acc0[g] += __shfl_xor(acc0[g], m, 64);
                        acc1[g] += __shfl_xor(acc1[g], m, 64);
                    }
                if (ks < 8) {
                    int g = ks, c0 = tl * 2, slot = prev & 63;
                    float v0 = acc0[g] + sh_b2[c0];
                    float v1 = acc1[g] + sh_b2[c0 + 1];
                    ring_blk[(slot * GW + g) * CW + c0]     = v0 > 0.f ? v0 : 0.f;
                    ring_blk[(slot * GW + g) * CW + c0 + 1] = v1 > 0.f ? v1 : 0.f;
                }
            }
            __syncthreads();
            if (tid < 128) {
                int n = sh_cnt[cg]; if (n > CAP) n = CAP;
                float a = 0.f;
                for (int i = 0; i < n; ++i)
                    a += ring_blk[(sh_list[cg * CAP + i] * GW + cg) * CW + cc];
                st_tag(xaf_c, xas_c, cg * CDIM + cbase + cc, a, tg, fast);
            }

            // ======= P3: gh GEMM (covers agg flight); poll agg; gi GEMM; gates =======
            if (tid < 192) {  // gh GEMM (rows 48..95) -> sh_gh
                const int tl = tid >> 4, ks = tid & 15;
                const float* wr = &sh_w[(48 + tl * 4) * WST];
                float acc[4][8] = {};
                #pragma unroll 4
                for (int j = 0; j < 16; ++j) {
                    int k = ks + j * 16;
                    float w0 = wr[k], w1 = wr[WST + k], w2 = wr[2 * WST + k], w3 = wr[3 * WST + k];
                    const float* ap = &sh_hold[k * AST];
                    #pragma unroll
                    for (int g = 0; g < 8; ++g) {
                        float a = ap[g];
                        acc[0][g] += w0 * a; acc[1][g] += w1 * a;
                        acc[2][g] += w2 * a; acc[3][g] += w3 * a;
                    }
                }
                #pragma unroll
                for (int m = 1; m < 16; m <<= 1)
                    #pragma unroll
                    for (int r = 0; r < 4; ++r)
                        #pragma unroll
                        for (int g = 0; g < 8; ++g)
                            acc[r][g] += __shfl_xor(acc[r][g], m, 64);
                if (ks < 8) {
                    int g = ks;
                    #pragma unroll
                    for (int r = 0; r < 4; ++r)
                        sh_gh[g * 48 + tl * 4 + r] = acc[r][g] + sh_bhh[tl * 4 + r];
                }
            }
            float av[8];
            poll_tag(xaf_c, xas_c, tg, tid, av, fast);
            #pragma unroll
            for (int j = 0; j < 8; ++j) sh_act[tid * AST + j] = av[j];
            __syncthreads();
            if (tid < 192) {  // gi GEMM (rows 0..47) -> sh_gi
                const int tl = tid >> 4, ks = tid & 15;
                const float* wr = &sh_w[(tl * 4) * WST];
                float acc[4][8] = {};
                #pragma unroll 4
                for (int j = 0; j < 16; ++j) {
                    int k = ks + j * 16;
                    float w0 = wr[k], w1 = wr[WST + k], w2 = wr[2 * WST + k], w3 = wr[3 * WST + k];
                    const float* ap = &sh_act[k * AST];
                    #pragma unroll
                    for (int g = 0; g < 8; ++g) {
                        float a = ap[g];
                        acc[0][g] += w0 * a; acc[1][g] += w1 * a;
                        acc[2][g] += w2 * a; acc[3][g] += w3 * a;
                    }
                }
                #pragma unroll
                for (int m = 1; m < 16; m <<= 1)
                    #pragma unroll
                    for (int r = 0; r < 4; ++r)
                        #pragma unroll
                        for (int g = 0; g < 8; ++g)
                            acc[r][g] += __shfl_xor(acc[r][g], m, 64);
                if (ks < 8) {
                    int g = ks;
                    #pragma unroll
                    for (int r = 0; r < 4; ++r)
                        sh_gi[g * 48 + tl * 4 + r] = acc[r][g] + sh_bih[tl * 4 + r];
                }
            }
            __syncthreads();
            if (tid < 128) {
                float ir = sh_gi[cg * 48 + cc], iz = sh_gi[cg * 48 + 16 + cc], in_ = sh_gi[cg * 48 + 32 + cc];
                float hr = sh_gh[cg * 48 + cc], hz = sh_gh[cg * 48 + 16 + cc], hn  = sh_gh[cg * 48 + 32 + cc];
                float hold = sh_hold[(cbase + cc) * AST + cg];
                float r  = 1.f / (1.f + expf(-(ir + hr)));
                float z_ = 1.f / (1.f + expf(-(iz + hz)));
                float nn = tanhf(in_ + r * hn);
                keep0 = (1.f - z_) * nn + z_ * hold;
                // pass0->pass1 hx handoff: drain our hx stores before the tag
                // that releases other blocks into pass 1.
                if (pass == 0 && s == NPER - 1)
                    asm volatile("s_waitcnt vmcnt(0)" ::: "memory");
                st_tag(xhf_c, xhs_c, cg * CDIM + cbase + cc, keep0, tg, fast);
            }
        }
    }
    if (tid < 128)
        st_sc(&hx[((size_t)(gb + cg) * NPER + 0) * CDIM + cbase + cc], keep0);
}

// ---------------- fallback (round-1 structure, known-correct) ----------------
__global__ __launch_bounds__(512)
void gnn_fallback(const float* __restrict__ x,
                  const float* __restrict__ W1, const float* __restrict__ b1,
                  const float* __restrict__ W2, const float* __restrict__ b2,
                  const float* __restrict__ w_ih, const float* __restrict__ b_ih,
                  const float* __restrict__ w_hh, const float* __restrict__ b_hh,
                  const int* __restrict__ src_f, const int* __restrict__ gid_f,
                  const float* __restrict__ msk_f,
                  const int* __restrict__ src_b, const int* __restrict__ gid_b,
                  const float* __restrict__ msk_b,
                  int Kf, int Kb, float* __restrict__ hx)
{
    const int b = blockIdx.x, t = threadIdx.x;
    __shared__ float sh_ring[64 * CDIM];
    __shared__ float sh_agg[CDIM], sh_hold[CDIM], sh_hnew[CDIM], sh_h1[CDIM];
    __shared__ float sh_gi[3 * CDIM], sh_gh[3 * CDIM];
    __shared__ int   sh_list[256];
    __shared__ int   sh_cnt;
    const size_t base = (size_t)b * NPER * CDIM;
    {
        const float4* x4 = (const float4*)(x + base);
        float4* h4 = (float4*)(hx + base);
        for (int i = t; i < NPER * CDIM / 4; i += 512) h4[i] = x4[i];
    }
    if (t == 0) sh_cnt = 0;
    __syncthreads();
    for (int pass = 0; pass < 2; ++pass) {
        const int* srcA = pass ? src_b : src_f;
        const int* gidA = pass ? gid_b : gid_f;
        const float* mskA = pass ? msk_b : msk_f;
        const int K = pass ? Kb : Kf;
        for (int step = 0; step < NPER; ++step) {
            const int node = pass ? (NPER - 1 - step) : step;
            if (t < CDIM / 4)
                ((float4*)sh_hold)[t] = ((const float4*)(hx + base + (size_t)node * CDIM))[t];
            for (int k = t; k < K; k += 512) {
                size_t off = (size_t)step * K + k;
                if (mskA[off] != 0.f && gidA[off] == b) {
                    int p = atomicAdd(&sh_cnt, 1);
                    if (p < 256) sh_list[p] = srcA[off] & 63;
                }
            }
            __syncthreads();
            int cnt = sh_cnt; if (cnt > 256) cnt = 256;
            if (t < CDIM) {
                float a = 0.f;
                for (int e = 0; e < cnt; ++e) a += sh_ring[sh_list[e] * CDIM + t];
                sh_agg[t] = a;
            }
            __syncthreads();
            #pragma unroll
            for (int d = 0; d < 3; ++d) {
                const int idx = t + d * 512;
                const float *wrow, *inv; float bias; float* outp;
                if (idx < 3 * CDIM) { wrow = w_ih + (size_t)idx * CDIM; inv = sh_agg; bias = b_ih[idx]; outp = &sh_gi[idx]; }
                else { int r = idx - 3 * CDIM; wrow = w_hh + (size_t)r * CDIM; inv = sh_hold; bias = b_hh[r]; outp = &sh_gh[r]; }
                float acc = 0.f;
                const float4* w4 = (const float4*)wrow; const float4* i4 = (const float4*)inv;
                #pragma unroll 8
                for (int j = 0; j < CDIM / 4; ++j) {
                    float4 w = w4[j], v = i4[j];
                    acc += w.x * v.x + w.y * v.y + w.z * v.z + w.w * v.w;
                }
                *outp = acc + bias;
            }
            __syncthreads();
            if (t < CDIM) {
                float ir = sh_gi[t], iz = sh_gi[t + CDIM], in_ = sh_gi[t + 2 * CDIM];
                float hr = sh_gh[t], hz = sh_gh[t + CDIM], hn = sh_gh[t + 2 * CDIM];
                float r = 1.f / (1.f + expf(-(ir + hr)));
                float z = 1.f / (1.f + expf(-(iz + hz)));
                float n = tanhf(in_ + r * hn);
                float hv = (1.f - z) * n + z * sh_hold[t];
                sh_hnew[t] = hv;
                hx[base + (size_t)node * CDIM + t] = hv;
            }
            if (t == 511) sh_cnt = 0;
            __syncthreads();
            if (t < CDIM) {
                const float4* w4 = (const float4*)(W1 + (size_t)t * CDIM);
                const float4* i4 = (const float4*)sh_hnew;
                float acc = 0.f;
                #pragma unroll 8
                for (int j = 0; j < CDIM / 4; ++j) {
                    float4 w = w4[j], v = i4[j];
                    acc += w.x * v.x + w.y * v.y + w.z * v.z + w.w * v.w;
                }
                acc += b1[t];
                sh_h1[t] = acc > 0.f ? acc : 0.f;
            }
            __syncthreads();
            if (t < CDIM) {
                const float4* w4 = (const float4*)(W2 + (size_t)t * CDIM);
                const float4* i4 = (const float4*)sh_h1;
                float acc = 0.f;
                #pragma unroll 8
                for (int j = 0; j < CDIM / 4; ++j) {
                    float4 w = w4[j], v = i4[j];
                    acc += w.x * v.x + w.y * v.y + w.z * v.z + w.w * v.w;
                }
                acc += b2[t];
                sh_ring[(node & 63) * CDIM + t] = acc > 0.f ? acc : 0.f;
            }
            __syncthreads();
        }
    }
}

extern "C" void kernel_launch(void* const* d_in, const int* in_sizes, int n_in,
                              void* d_out, int out_size, void* d_ws, size_t ws_size,
                              hipStream_t stream) {
    const float* x    = (const float*)d_in[0];
    const float* W1   = (const float*)d_in[1];
    const float* b1   = (const float*)d_in[2];
    const float* W2   = (const float*)d_in[3];
    const float* b2   = (const float*)d_in[4];
    const float* w_ih = (const float*)d_in[5];
    const float* b_ih = (const float*)d_in[6];
    const float* w_hh = (const float*)d_in[7];
    const float* b_hh = (const float*)d_in[8];
    const int*   src_f = (const int*)d_in[9];
    const int*   gid_f = (const int*)d_in[10];
    const float* msk_f = (const float*)d_in[11];
    const int*   src_b = (const int*)d_in[12];
    const int*   gid_b = (const int*)d_in[13];
    const float* msk_b = (const float*)d_in[14];

    const int Kf = in_sizes[9]  / NPER;
    const int Kb = in_sizes[12] / NPER;
    float* hx = (float*)d_out;

    char* ws = (char*)d_ws;
    // ws layout: [0,4096) det slots | 6 tagged exchange buffers
    // (fast/safe x h/z/a, each 64 graphs x 256 ch x 8B) | ring
    const size_t XBUF = (size_t)BG * CDIM * 2;  // floats per buffer (8B/elem)
    const size_t need = 4096 + 6 * XBUF * 4 + (size_t)NB * 64 * GW * CW * 4;
    if (ws_size >= need) {
        int*   det  = (int*)ws;
        float* xhf  = (float*)(ws + 4096);
        float* xhs  = xhf + XBUF;
        float* xzf  = xhs + XBUF;
        float* xzs  = xzf + XBUF;
        float* xaf  = xzs + XBUF;
        float* xas  = xaf + XBUF;
        float* ring = xas + XBUF;
        // zero det (512 u64) + 6*64*256 = 98304 u64 tag pairs => 98816 u64
        init_ws<<<386, 256, 0, stream>>>((unsigned long long*)ws, 512 + 6 * BG * CDIM);
        gnn_fp32<<<NB, TPB, 0, stream>>>(
            x, W1, b1, W2, b2, w_ih, b_ih, w_hh, b_hh,
            src_f, gid_f, msk_f, src_b, gid_b, msk_b,
            Kf, Kb, hx, xhf, xhs, xzf, xzs, xaf, xas, ring, det);
    } else {
        gnn_fallback<<<BG, 512, 0, stream>>>(
            x, W1, b1, W2, b2, w_ih, b_ih, w_hh, b_hh,
            src_f, gid_f, msk_f, src_b, gid_b, msk_b,
            Kf, Kb, hx);
    }
}

// Round 6
// 19031.984 us; speedup vs baseline: 6.0416x; 2.0333x over previous
//
#include <hip/hip_runtime.h>

#define NPER 512
#define CDIM 256
#define BG   64
#define NB   128
#define TPB  256
#define GW   8      // graphs per cluster
#define CW   16     // channels per member block
#define WST  258    // col-major weight stride (256 + 2): bank stride 2 -> free
#define AST  10     // k-major activation stride (8 graphs + 2 pad)
#define CAP  64

// Zero the tagged exchange buffers (tags must be 0 so step-1 polls for tag 0
// succeed immediately, and stale tags from a previous replay can't alias).
__global__ void init_ws(unsigned long long* p, int n) {
    int i = blockIdx.x * blockDim.x + threadIdx.x;
    if (i < n) p[i] = 0ULL;
}

__device__ __forceinline__ float ld_sc(const float* p) {
    return __hip_atomic_load((const float*)p, __ATOMIC_RELAXED, __HIP_MEMORY_SCOPE_AGENT);
}
__device__ __forceinline__ void st_sc(float* p, float v) {
    __hip_atomic_store(p, v, __ATOMIC_RELAXED, __HIP_MEMORY_SCOPE_AGENT);
}
// One 8B atomic store carries (value, tag) together: no fence / store-order
// assumption anywhere in the protocol. Agent scope (LLC-homed) -- the proven
// round-1 transport; all faster-cache variants were falsified in r2-r4.
__device__ __forceinline__ void st_tag(float* buf, int idx, float v, unsigned tg) {
    unsigned long long u = ((unsigned long long)tg << 32) |
                           (unsigned long long)__float_as_uint(v);
    __hip_atomic_store((unsigned long long*)(buf + 2 * (size_t)idx), u,
                       __ATOMIC_RELAXED, __HIP_MEMORY_SCOPE_AGENT);
}

// Poll one GROUP's quarter (4 graphs x 256 ch = 1024 pairs) of a cluster
// exchange buffer until every (value,tag) pair carries `tg`. Detection and
// data arrive in the same LLC round-trip. jb = group's pair-row base (0 or 4).
// Single-buffer WAR safety: per group, the step chain (hnew->z->agg->hnew)
// guarantees a producer writing step t has observed all step-t inputs, which
// implies every consumer finished its step t-1 reads -- the round-1 argument,
// applied per group (groups use disjoint pair ranges).
__device__ __forceinline__ void poll_tag4(const float* buf, unsigned tg, int tid,
                                          int jb, float* vals) {
    unsigned long long u[4];
    int ok = 0;
    do {
        if (!ok) {
            #pragma unroll
            for (int j = 0; j < 4; ++j)
                u[j] = __hip_atomic_load(
                    (const unsigned long long*)(buf + 2 * (size_t)((jb + j) * TPB + tid)),
                    __ATOMIC_RELAXED, __HIP_MEMORY_SCOPE_AGENT);
            ok = 1;
            #pragma unroll
            for (int j = 0; j < 4; ++j) ok &= ((unsigned)(u[j] >> 32) == tg);
        }
    } while (!__syncthreads_and(ok));
    #pragma unroll
    for (int j = 0; j < 4; ++j) vals[j] = __uint_as_float((unsigned)(u[j] & 0xffffffffu));
}

__global__ __launch_bounds__(TPB, 1)
void gnn_fp32(const float* __restrict__ x,
              const float* __restrict__ W1g, const float* __restrict__ b1g,
              const float* __restrict__ W2g, const float* __restrict__ b2g,
              const float* __restrict__ wihg, const float* __restrict__ bihg,
              const float* __restrict__ whhg, const float* __restrict__ bhhg,
              const int* __restrict__ src_f, const int* __restrict__ gid_f,
              const float* __restrict__ msk_f,
              const int* __restrict__ src_b, const int* __restrict__ gid_b,
              const float* __restrict__ msk_b,
              int Kf, int Kb,
              float* __restrict__ hx,
              float* __restrict__ xh, float* __restrict__ xz,
              float* __restrict__ xa, float* __restrict__ ring)
{
    __shared__ float sh_w[128 * WST];    // col-major rows: 0-47 wih, 48-95 whh, 96-111 W1, 112-127 W2
    __shared__ float sh_act[256 * AST];
    __shared__ float sh_hold[256 * AST];
    __shared__ float sh_gi[GW * 48];
    __shared__ float sh_gh[GW * 48];
    __shared__ int   sh_list[GW * CAP];
    __shared__ int   sh_cnt[GW];
    __shared__ float sh_bih[48], sh_bhh[48], sh_b1[CW], sh_b2[CW];

    const int tid   = threadIdx.x;
    const int cl    = blockIdx.x & 7;
    const int mb    = blockIdx.x >> 3;
    const int gb    = cl * GW;
    const int cbase = mb * CW;

    float* xh_c = xh + (size_t)cl * GW * CDIM * 2;
    float* xz_c = xz + (size_t)cl * GW * CDIM * 2;
    float* xa_c = xa + (size_t)cl * GW * CDIM * 2;
    float* ring_blk = ring + (size_t)blockIdx.x * 64 * GW * CW;

    // ---- stage weights col-major into LDS, once ----
    for (int e = tid; e < 128 * 256; e += TPB) {
        int r = e >> 8, k = e & 255;
        const float* sp; int grow;
        if (r < 48)       { sp = wihg; grow = (r >> 4) * CDIM + cbase + (r & 15); }
        else if (r < 96)  { sp = whhg; grow = ((r - 48) >> 4) * CDIM + cbase + ((r - 48) & 15); }
        else if (r < 112) { sp = W1g;  grow = cbase + (r - 96); }
        else              { sp = W2g;  grow = cbase + (r - 112); }
        sh_w[r * WST + k] = sp[(size_t)grow * CDIM + k];
    }
    if (tid < 48) {
        sh_bih[tid] = bihg[(tid >> 4) * CDIM + cbase + (tid & 15)];
        sh_bhh[tid] = bhhg[(tid >> 4) * CDIM + cbase + (tid & 15)];
    } else if (tid < 64) {
        sh_b1[tid - 48] = b1g[cbase + tid - 48];
        sh_b2[tid - 48] = b2g[cbase + tid - 48];
    }
    __syncthreads();

    float keep0 = 0.f;
    const int cg = tid >> 4;       // for tid<128: graph-in-cluster 0..7
    const int cc = tid & 15;       // channel within block's 16
    const int mygrp = tid >> 6;    // for tid<128: 0 for graphs 0-3, 1 for 4-7

    for (int pass = 0; pass < 2; ++pass) {
        const int* srcA   = pass ? src_b : src_f;
        const int* gidA   = pass ? gid_b : gid_f;
        const float* mskA = pass ? msk_b : msk_f;
        const int K = pass ? Kb : Kf;

        for (int s = 0; s < NPER; ++s) {
            const int node = pass ? (NPER - 1 - s) : s;
            const unsigned tg = (unsigned)(pass * NPER + s + 1);
            const bool has_prev = !(pass == 0 && s == 0);
            const int prev = (s > 0) ? (pass ? node + 1 : node - 1) : (NPER - 1);

            // ================= P1 (groups A,B): deferred hx write; stage hnew +
            // h_old; W1 GEMM -> z tagged; edge filter at B-tail =================
            #pragma unroll
            for (int grp = 0; grp < 2; ++grp) {
                const int gbase = grp * 4;
                if (has_prev && tid < 128 && mygrp == grp)
                    st_sc(&hx[((size_t)(gb + cg) * NPER + prev) * CDIM + cbase + cc], keep0);
                float holdv[4];
                if (pass == 1 && s > 0) {          // issue early: completes under the poll
                    #pragma unroll
                    for (int j = 0; j < 4; ++j)
                        holdv[j] = ld_sc(&hx[((size_t)(gb + gbase + j) * NPER + node) * CDIM + tid]);
                }
                if (grp == 0 && tid < GW) sh_cnt[tid] = 0;

                float hv[4];
                poll_tag4(xh_c, tg - 1, tid, gbase, hv);   // tag 0 at (pass0,s0): zeros
                #pragma unroll
                for (int j = 0; j < 4; ++j) sh_act[tid * AST + gbase + j] = hv[j];
                if (pass == 0) {                   // h_old = x (read-only cached loads)
                    int sg = tid & 3, skb = (tid >> 2) << 2;
                    const float* op = x + ((size_t)(gb + gbase + sg) * NPER + node) * CDIM + skb;
                    float4 h0 = *(const float4*)op;
                    float* d = &sh_hold[skb * AST + gbase + sg];
                    d[0] = h0.x; d[AST] = h0.y; d[2*AST] = h0.z; d[3*AST] = h0.w;
                } else if (s == 0) {               // h_old(node 511) == hnew from fwd end
                    #pragma unroll
                    for (int j = 0; j < 4; ++j) sh_hold[tid * AST + gbase + j] = hv[j];
                } else {
                    #pragma unroll
                    for (int j = 0; j < 4; ++j) sh_hold[tid * AST + gbase + j] = holdv[j];
                }
                __syncthreads();

                {   // W1 GEMM (rows 96..111), group grp -> z tagged
                    const int tl = tid >> 5, ks = tid & 31;
                    const float* wr0 = &sh_w[(96 + tl * 2) * WST];
                    const float* wr1 = wr0 + WST;
                    float acc0[4] = {}, acc1[4] = {};
                    #pragma unroll
                    for (int j = 0; j < 8; ++j) {
                        int k = ks + j * 32;
                        float w0 = wr0[k], w1 = wr1[k];
                        const float* ap = &sh_act[k * AST + gbase];
                        #pragma unroll
                        for (int g = 0; g < 4; ++g) {
                            float a = ap[g];
                            acc0[g] += w0 * a; acc1[g] += w1 * a;
                        }
                    }
                    #pragma unroll
                    for (int m = 1; m < 32; m <<= 1)
                        #pragma unroll
                        for (int g = 0; g < 4; ++g) {
                            acc0[g] += __shfl_xor(acc0[g], m, 64);
                            acc1[g] += __shfl_xor(acc1[g], m, 64);
                        }
                    if (ks < 4) {
                        int g = gbase + ks, c0 = tl * 2;
                        float v0 = acc0[ks] + sh_b1[c0];
                        float v1 = acc1[ks] + sh_b1[c0 + 1];
                        st_tag(xz_c, g * CDIM + cbase + c0,     v0 > 0.f ? v0 : 0.f, tg);
                        st_tag(xz_c, g * CDIM + cbase + c0 + 1, v1 > 0.f ? v1 : 0.f, tg);
                    }
                }
                if (grp == 1) {   // edge filter (both groups): covers z flight
                    for (int e = tid; e < K; e += TPB) {
                        size_t off = (size_t)s * K + e;
                        if (mskA[off] != 0.f) {
                            int g = gidA[off] - gb;
                            if ((unsigned)g < GW) {
                                int p = atomicAdd(&sh_cnt[g], 1);
                                if (p < CAP) sh_list[g * CAP + p] = srcA[off] & 63;
                            }
                        }
                    }
                }
            }

            // ================= P2 (groups A,B): poll z; ring = relu(W2 z);
            // aggregate -> agg tagged =================
            #pragma unroll
            for (int grp = 0; grp < 2; ++grp) {
                const int gbase = grp * 4;
                float zv[4];
                poll_tag4(xz_c, tg, tid, gbase, zv);
                #pragma unroll
                for (int j = 0; j < 4; ++j) sh_act[tid * AST + gbase + j] = zv[j];
                __syncthreads();

                {   // W2 GEMM (rows 112..127), group grp -> ring[prev & 63]
                    const int tl = tid >> 5, ks = tid & 31;
                    const float* wr0 = &sh_w[(112 + tl * 2) * WST];
                    const float* wr1 = wr0 + WST;
                    float acc0[4] = {}, acc1[4] = {};
                    #pragma unroll
                    for (int j = 0; j < 8; ++j) {
                        int k = ks + j * 32;
                        float w0 = wr0[k], w1 = wr1[k];
                        const float* ap = &sh_act[k * AST + gbase];
                        #pragma unroll
                        for (int g = 0; g < 4; ++g) {
                            float a = ap[g];
                            acc0[g] += w0 * a; acc1[g] += w1 * a;
                        }
                    }
                    #pragma unroll
                    for (int m = 1; m < 32; m <<= 1)
                        #pragma unroll
                        for (int g = 0; g < 4; ++g) {
                            acc0[g] += __shfl_xor(acc0[g], m, 64);
                            acc1[g] += __shfl_xor(acc1[g], m, 64);
                        }
                    if (ks < 4) {
                        int g = gbase + ks, c0 = tl * 2, slot = prev & 63;
                        float v0 = acc0[ks] + sh_b2[c0];
                        float v1 = acc1[ks] + sh_b2[c0 + 1];
                        ring_blk[(slot * GW + g) * CW + c0]     = v0 > 0.f ? v0 : 0.f;
                        ring_blk[(slot * GW + g) * CW + c0 + 1] = v1 > 0.f ? v1 : 0.f;
                    }
                }
                __syncthreads();
                if (tid < 128 && mygrp == grp) {
                    int n = sh_cnt[cg]; if (n > CAP) n = CAP;
                    float a = 0.f;
                    for (int i = 0; i < n; ++i)
                        a += ring_blk[(sh_list[cg * CAP + i] * GW + cg) * CW + cc];
                    st_tag(xa_c, cg * CDIM + cbase + cc, a, tg);
                }
            }

            // ================= P3 (groups A,B): gh GEMM (covers agg flight);
            // poll agg; gi GEMM; gates -> hnew tagged =================
            #pragma unroll
            for (int grp = 0; grp < 2; ++grp) {
                const int gbase = grp * 4;
                if (tid < 192) {  // gh GEMM (rows 48..95), group grp -> sh_gh
                    const int tl = tid >> 4, ks = tid & 15;
                    const float* wr = &sh_w[(48 + tl * 4) * WST];
                    float acc[4][4] = {};
                    #pragma unroll 4
                    for (int j = 0; j < 16; ++j) {
                        int k = ks + j * 16;
                        float w0 = wr[k], w1 = wr[WST + k], w2 = wr[2 * WST + k], w3 = wr[3 * WST + k];
                        const float* ap = &sh_hold[k * AST + gbase];
                        #pragma unroll
                        for (int g = 0; g < 4; ++g) {
                            float a = ap[g];
                            acc[0][g] += w0 * a; acc[1][g] += w1 * a;
                            acc[2][g] += w2 * a; acc[3][g] += w3 * a;
                        }
                    }
                    #pragma unroll
                    for (int m = 1; m < 16; m <<= 1)
                        #pragma unroll
                        for (int r = 0; r < 4; ++r)
                            #pragma unroll
                            for (int g = 0; g < 4; ++g)
                                acc[r][g] += __shfl_xor(acc[r][g], m, 64);
                    if (ks < 4) {
                        #pragma unroll
                        for (int r = 0; r < 4; ++r)
                            sh_gh[(gbase + ks) * 48 + tl * 4 + r] = acc[r][ks] + sh_bhh[tl * 4 + r];
                    }
                }
                float av[4];
                poll_tag4(xa_c, tg, tid, gbase, av);
                #pragma unroll
                for (int j = 0; j < 4; ++j) sh_act[tid * AST + gbase + j] = av[j];
                __syncthreads();
                if (tid < 192) {  // gi GEMM (rows 0..47), group grp -> sh_gi
                    const int tl = tid >> 4, ks = tid & 15;
                    const float* wr = &sh_w[(tl * 4) * WST];
                    float acc[4][4] = {};
                    #pragma unroll 4
                    for (int j = 0; j < 16; ++j) {
                        int k = ks + j * 16;
                        float w0 = wr[k], w1 = wr[WST + k], w2 = wr[2 * WST + k], w3 = wr[3 * WST + k];
                        const float* ap = &sh_act[k * AST + gbase];
                        #pragma unroll
                        for (int g = 0; g < 4; ++g) {
                            float a = ap[g];
                            acc[0][g] += w0 * a; acc[1][g] += w1 * a;
                            acc[2][g] += w2 * a; acc[3][g] += w3 * a;
                        }
                    }
                    #pragma unroll
                    for (int m = 1; m < 16; m <<= 1)
                        #pragma unroll
                        for (int r = 0; r < 4; ++r)
                            #pragma unroll
                            for (int g = 0; g < 4; ++g)
                                acc[r][g] += __shfl_xor(acc[r][g], m, 64);
                    if (ks < 4) {
                        #pragma unroll
                        for (int r = 0; r < 4; ++r)
                            sh_gi[(gbase + ks) * 48 + tl * 4 + r] = acc[r][ks] + sh_bih[tl * 4 + r];
                    }
                }
                __syncthreads();
                if (tid < 128 && mygrp == grp) {
                    float ir = sh_gi[cg * 48 + cc], iz = sh_gi[cg * 48 + 16 + cc], in_ = sh_gi[cg * 48 + 32 + cc];
                    float hr = sh_gh[cg * 48 + cc], hz = sh_gh[cg * 48 + 16 + cc], hn  = sh_gh[cg * 48 + 32 + cc];
                    float hold = sh_hold[(cbase + cc) * AST + cg];
                    float r  = 1.f / (1.f + expf(-(ir + hr)));
                    float z_ = 1.f / (1.f + expf(-(iz + hz)));
                    float nn = tanhf(in_ + r * hn);
                    keep0 = (1.f - z_) * nn + z_ * hold;
                    // pass0->pass1 hx handoff: drain this thread's hx stores
                    // before the tag that releases other blocks into pass 1.
                    if (pass == 0 && s == NPER - 1)
                        asm volatile("s_waitcnt vmcnt(0)" ::: "memory");
                    st_tag(xh_c, cg * CDIM + cbase + cc, keep0, tg);
                }
            }
        }
    }
    if (tid < 128)
        st_sc(&hx[((size_t)(gb + cg) * NPER + 0) * CDIM + cbase + cc], keep0);
}

// ---------------- fallback (round-1 structure, known-correct) ----------------
__global__ __launch_bounds__(512)
void gnn_fallback(const float* __restrict__ x,
                  const float* __restrict__ W1, const float* __restrict__ b1,
                  const float* __restrict__ W2, const float* __restrict__ b2,
                  const float* __restrict__ w_ih, const float* __restrict__ b_ih,
                  const float* __restrict__ w_hh, const float* __restrict__ b_hh,
                  const int* __restrict__ src_f, const int* __restrict__ gid_f,
                  const float* __restrict__ msk_f,
                  const int* __restrict__ src_b, const int* __restrict__ gid_b,
                  const float* __restrict__ msk_b,
                  int Kf, int Kb, float* __restrict__ hx)
{
    const int b = blockIdx.x, t = threadIdx.x;
    __shared__ float sh_ring[64 * CDIM];
    __shared__ float sh_agg[CDIM], sh_hold[CDIM], sh_hnew[CDIM], sh_h1[CDIM];
    __shared__ float sh_gi[3 * CDIM], sh_gh[3 * CDIM];
    __shared__ int   sh_list[256];
    __shared__ int   sh_cnt;
    const size_t base = (size_t)b * NPER * CDIM;
    {
        const float4* x4 = (const float4*)(x + base);
        float4* h4 = (float4*)(hx + base);
        for (int i = t; i < NPER * CDIM / 4; i += 512) h4[i] = x4[i];
    }
    if (t == 0) sh_cnt = 0;
    __syncthreads();
    for (int pass = 0; pass < 2; ++pass) {
        const int* srcA = pass ? src_b : src_f;
        const int* gidA = pass ? gid_b : gid_f;
        const float* mskA = pass ? msk_b : msk_f;
        const int K = pass ? Kb : Kf;
        for (int step = 0; step < NPER; ++step) {
            const int node = pass ? (NPER - 1 - step) : step;
            if (t < CDIM / 4)
                ((float4*)sh_hold)[t] = ((const float4*)(hx + base + (size_t)node * CDIM))[t];
            for (int k = t; k < K; k += 512) {
                size_t off = (size_t)step * K + k;
                if (mskA[off] != 0.f && gidA[off] == b) {
                    int p = atomicAdd(&sh_cnt, 1);
                    if (p < 256) sh_list[p] = srcA[off] & 63;
                }
            }
            __syncthreads();
            int cnt = sh_cnt; if (cnt > 256) cnt = 256;
            if (t < CDIM) {
                float a = 0.f;
                for (int e = 0; e < cnt; ++e) a += sh_ring[sh_list[e] * CDIM + t];
                sh_agg[t] = a;
            }
            __syncthreads();
            #pragma unroll
            for (int d = 0; d < 3; ++d) {
                const int idx = t + d * 512;
                const float *wrow, *inv; float bias; float* outp;
                if (idx < 3 * CDIM) { wrow = w_ih + (size_t)idx * CDIM; inv = sh_agg; bias = b_ih[idx]; outp = &sh_gi[idx]; }
                else { int r = idx - 3 * CDIM; wrow = w_hh + (size_t)r * CDIM; inv = sh_hold; bias = b_hh[r]; outp = &sh_gh[r]; }
                float acc = 0.f;
                const float4* w4 = (const float4*)wrow; const float4* i4 = (const float4*)inv;
                #pragma unroll 8
                for (int j = 0; j < CDIM / 4; ++j) {
                    float4 w = w4[j], v = i4[j];
                    acc += w.x * v.x + w.y * v.y + w.z * v.z + w.w * v.w;
                }
                *outp = acc + bias;
            }
            __syncthreads();
            if (t < CDIM) {
                float ir = sh_gi[t], iz = sh_gi[t + CDIM], in_ = sh_gi[t + 2 * CDIM];
                float hr = sh_gh[t], hz = sh_gh[t + CDIM], hn = sh_gh[t + 2 * CDIM];
                float r = 1.f / (1.f + expf(-(ir + hr)));
                float z = 1.f / (1.f + expf(-(iz + hz)));
                float n = tanhf(in_ + r * hn);
                float hv = (1.f - z) * n + z * sh_hold[t];
                sh_hnew[t] = hv;
                hx[base + (size_t)node * CDIM + t] = hv;
            }
            if (t == 511) sh_cnt = 0;
            __syncthreads();
            if (t < CDIM) {
                const float4* w4 = (const float4*)(W1 + (size_t)t * CDIM);
                const float4* i4 = (const float4*)sh_hnew;
                float acc = 0.f;
                #pragma unroll 8
                for (int j = 0; j < CDIM / 4; ++j) {
                    float4 w = w4[j], v = i4[j];
                    acc += w.x * v.x + w.y * v.y + w.z * v.z + w.w * v.w;
                }
                acc += b1[t];
                sh_h1[t] = acc > 0.f ? acc : 0.f;
            }
            __syncthreads();
            if (t < CDIM) {
                const float4* w4 = (const float4*)(W2 + (size_t)t * CDIM);
                const float4* i4 = (const float4*)sh_h1;
                float acc = 0.f;
                #pragma unroll 8
                for (int j = 0; j < CDIM / 4; ++j) {
                    float4 w = w4[j], v = i4[j];
                    acc += w.x * v.x + w.y * v.y + w.z * v.z + w.w * v.w;
                }
                acc += b2[t];
                sh_ring[(node & 63) * CDIM + t] = acc > 0.f ? acc : 0.f;
            }
            __syncthreads();
        }
    }
}

extern "C" void kernel_launch(void* const* d_in, const int* in_sizes, int n_in,
                              void* d_out, int out_size, void* d_ws, size_t ws_size,
                              hipStream_t stream) {
    const float* x    = (const float*)d_in[0];
    const float* W1   = (const float*)d_in[1];
    const float* b1   = (const float*)d_in[2];
    const float* W2   = (const float*)d_in[3];
    const float* b2   = (const float*)d_in[4];
    const float* w_ih = (const float*)d_in[5];
    const float* b_ih = (const float*)d_in[6];
    const float* w_hh = (const float*)d_in[7];
    const float* b_hh = (const float*)d_in[8];
    const int*   src_f = (const int*)d_in[9];
    const int*   gid_f = (const int*)d_in[10];
    const float* msk_f = (const float*)d_in[11];
    const int*   src_b = (const int*)d_in[12];
    const int*   gid_b = (const int*)d_in[13];
    const float* msk_b = (const float*)d_in[14];

    const int Kf = in_sizes[9]  / NPER;
    const int Kb = in_sizes[12] / NPER;
    float* hx = (float*)d_out;

    char* ws = (char*)d_ws;
    // 4096 pad + 3 tagged exchange buffers (64 graphs x 256 ch x 8B) + ring
    const size_t need = 4096 + 3 * (size_t)BG * CDIM * 8 + (size_t)NB * 64 * GW * CW * 4;
    if (ws_size >= need) {
        float* xh   = (float*)(ws + 4096);
        float* xz   = xh + (size_t)BG * CDIM * 2;
        float* xa   = xz + (size_t)BG * CDIM * 2;
        float* ring = xa + (size_t)BG * CDIM * 2;
        // 3 * 64 * 256 = 49152 u64 pairs to zero; 192 * 256 threads covers exactly.
        init_ws<<<192, 256, 0, stream>>>((unsigned long long*)(ws + 4096), 3 * BG * CDIM);
        gnn_fp32<<<NB, TPB, 0, stream>>>(
            x, W1, b1, W2, b2, w_ih, b_ih, w_hh, b_hh,
            src_f, gid_f, msk_f, src_b, gid_b, msk_b,
            Kf, Kb, hx, xh, xz, xa, ring);
    } else {
        gnn_fallback<<<BG, 512, 0, stream>>>(
            x, W1, b1, W2, b2, w_ih, b_ih, w_hh, b_hh,
            src_f, gid_f, msk_f, src_b, gid_b, msk_b,
            Kf, Kb, hx);
    }
}

// Round 7
// 18190.259 us; speedup vs baseline: 6.3211x; 1.0463x over previous
//
#include <hip/hip_runtime.h>

#define NPER 512
#define CDIM 256
#define BG   64
#define NB   128
#define TPB  256
#define GW   8      // graphs per cluster
#define CW   16     // channels per member block
#define WST  258    // col-major weight stride (256 + 2): bank stride 2
#define A2   130    // act/hold sub-row stride (128 + 2): all GEMM reads <=2-way
#define CAP  64

// Zero the tagged exchange buffers (tags must be 0 so step-1 polls for tag 0
// succeed immediately, and stale tags from a previous replay can't alias).
__global__ void init_ws(unsigned long long* p, int n) {
    int i = blockIdx.x * blockDim.x + threadIdx.x;
    if (i < n) p[i] = 0ULL;
}

__device__ __forceinline__ float ld_sc(const float* p) {
    return __hip_atomic_load((const float*)p, __ATOMIC_RELAXED, __HIP_MEMORY_SCOPE_AGENT);
}
__device__ __forceinline__ void st_sc(float* p, float v) {
    __hip_atomic_store(p, v, __ATOMIC_RELAXED, __HIP_MEMORY_SCOPE_AGENT);
}
// One 8B atomic store carries (value, tag) together: no fence / store-order
// assumption anywhere. Agent scope (LLC-homed) -- the proven r1 transport;
// all faster-cache variants were falsified in r2-r4.
__device__ __forceinline__ void st_tag(float* buf, int idx, float v, unsigned tg) {
    unsigned long long u = ((unsigned long long)tg << 32) |
                           (unsigned long long)__float_as_uint(v);
    __hip_atomic_store((unsigned long long*)(buf + 2 * (size_t)idx), u,
                       __ATOMIC_RELAXED, __HIP_MEMORY_SCOPE_AGENT);
}

// WAVE-level poll of this wave's 2-graph slice (512 pairs, 8 per lane).
// Detection and data arrive in the same LLC round-trip. No block barrier:
// __all is a wave-wide AND. Chain = {wave w of the cluster's 16 blocks};
// the r1 single-buffer WAR/deadlock induction applies verbatim per chain
// (chains use disjoint pair ranges and never wait on each other).
__device__ __forceinline__ void poll_w(const float* buf, unsigned tg,
                                       int b0, int b1, int L, float* vals) {
    unsigned long long u[8];
    int ok = 0;
    do {
        if (!ok) {
            #pragma unroll
            for (int g = 0; g < 2; ++g)
                #pragma unroll
                for (int j = 0; j < 4; ++j) {
                    int p = (g ? b1 : b0) + j * 64 + L;
                    u[g * 4 + j] = __hip_atomic_load(
                        (const unsigned long long*)(buf + 2 * (size_t)p),
                        __ATOMIC_RELAXED, __HIP_MEMORY_SCOPE_AGENT);
                }
            ok = 1;
            #pragma unroll
            for (int q = 0; q < 8; ++q) ok &= ((unsigned)(u[q] >> 32) == tg);
        }
    } while (!__all(ok));
    #pragma unroll
    for (int q = 0; q < 8; ++q) vals[q] = __uint_as_float((unsigned)(u[q] & 0xffffffffu));
}

__global__ __launch_bounds__(TPB, 1)
void gnn_fp32(const float* __restrict__ x,
              const float* __restrict__ W1g, const float* __restrict__ b1g,
              const float* __restrict__ W2g, const float* __restrict__ b2g,
              const float* __restrict__ wihg, const float* __restrict__ bihg,
              const float* __restrict__ whhg, const float* __restrict__ bhhg,
              const int* __restrict__ src_f, const int* __restrict__ gid_f,
              const float* __restrict__ msk_f,
              const int* __restrict__ src_b, const int* __restrict__ gid_b,
              const float* __restrict__ msk_b,
              int Kf, int Kb,
              float* __restrict__ hx,
              float* __restrict__ xh, float* __restrict__ xz,
              float* __restrict__ xa, float* __restrict__ ring)
{
    // Read-only after init barrier:
    __shared__ float sh_w[128 * WST];   // rows: 0-47 wih, 48-95 whh, 96-111 W1, 112-127 W2
    __shared__ float sh_bih[48], sh_bhh[48], sh_b1[CW], sh_b2[CW];
    // Wave-private regions (no cross-wave access -> no barriers in main loop):
    __shared__ float sh_act[4][4 * A2];    // [wave][(g*2+half)*A2 + kk]
    __shared__ float sh_hold[4][4 * A2];
    __shared__ float sh_gi[4][2][48];
    __shared__ float sh_gh[4][2][48];
    __shared__ int   sh_list[4][2][CAP];
    __shared__ int   sh_cnt[4][2];

    const int tid   = threadIdx.x;
    const int w     = tid >> 6;          // wave 0..3
    const int L     = tid & 63;          // lane
    const int cl    = blockIdx.x & 7;
    const int mb    = blockIdx.x >> 3;
    const int gb    = cl * GW;
    const int g0    = gb + 2 * w;        // wave's first global graph
    const int cbase = mb * CW;

    float* ring_blk = ring + (size_t)blockIdx.x * 64 * GW * CW;

    // ---- stage weights col-major into LDS, once (cooperative) ----
    for (int e = tid; e < 128 * 256; e += TPB) {
        int r = e >> 8, k = e & 255;
        const float* sp; int grow;
        if (r < 48)       { sp = wihg; grow = (r >> 4) * CDIM + cbase + (r & 15); }
        else if (r < 96)  { sp = whhg; grow = ((r - 48) >> 4) * CDIM + cbase + ((r - 48) & 15); }
        else if (r < 112) { sp = W1g;  grow = cbase + (r - 96); }
        else              { sp = W2g;  grow = cbase + (r - 112); }
        sh_w[r * WST + k] = sp[(size_t)grow * CDIM + k];
    }
    if (tid < 48) {
        sh_bih[tid] = bihg[(tid >> 4) * CDIM + cbase + (tid & 15)];
        sh_bhh[tid] = bhhg[(tid >> 4) * CDIM + cbase + (tid & 15)];
    } else if (tid < 64) {
        sh_b1[tid - 48] = b1g[cbase + tid - 48];
        sh_b2[tid - 48] = b2g[cbase + tid - 48];
    }
    __syncthreads();   // the ONLY block barrier; sh_w/biases read-only after

    float keep = 0.f;  // live in lanes 0..31: (g = L>>4, c = L&15)

    for (int pass = 0; pass < 2; ++pass) {
        const int* srcA   = pass ? src_b : src_f;
        const int* gidA   = pass ? gid_b : gid_f;
        const float* mskA = pass ? msk_b : msk_f;
        const int K = pass ? Kb : Kf;

        for (int s = 0; s < NPER; ++s) {
            const int node = pass ? (NPER - 1 - s) : s;
            const unsigned tg = (unsigned)(pass * NPER + s + 1);
            const bool has_prev = !(pass == 0 && s == 0);
            const int prev = (s > 0) ? (pass ? node + 1 : node - 1) : (NPER - 1);
            const int b0 = (g0) * CDIM, b1 = (g0 + 1) * CDIM;

            // ======= P1: deferred hx write; hold prefetch; poll hnew; W1 -> z;
            //         edge filter (covers z flight) =======
            if (has_prev && L < 32) {
                int g = L >> 4, c = L & 15;
                st_sc(&hx[((size_t)(g0 + g) * NPER + prev) * CDIM + cbase + c], keep);
            }
            if (L < 2) sh_cnt[w][L] = 0;
            float holdv[8];
            if (pass == 1 && s > 0) {            // issue early: completes under the poll
                #pragma unroll
                for (int g = 0; g < 2; ++g)
                    #pragma unroll
                    for (int j = 0; j < 4; ++j)
                        holdv[g * 4 + j] =
                            ld_sc(&hx[((size_t)(g0 + g) * NPER + node) * CDIM + j * 64 + L]);
            }

            float hv[8];
            poll_w(xh, tg - 1, b0, b1, L, hv);   // tag 0 at (pass0,s0): zeros, harmless
            #pragma unroll
            for (int g = 0; g < 2; ++g)
                #pragma unroll
                for (int j = 0; j < 4; ++j) {
                    int k = j * 64 + L;
                    sh_act[w][(g * 2 + (j >> 1)) * A2 + (k & 127)] = hv[g * 4 + j];
                }
            if (pass == 0) {                     // h_old = x (read-only cached loads)
                #pragma unroll
                for (int g = 0; g < 2; ++g) {
                    const float* op = x + ((size_t)(g0 + g) * NPER + node) * CDIM + 4 * L;
                    float4 h0 = *(const float4*)op;
                    int k = 4 * L;
                    float* d = &sh_hold[w][(g * 2 + (k >> 7)) * A2 + (k & 127)];
                    d[0] = h0.x; d[1] = h0.y; d[2] = h0.z; d[3] = h0.w;
                }
            } else if (s == 0) {                 // h_old(node 511) == hnew from fwd end
                #pragma unroll
                for (int g = 0; g < 2; ++g)
                    #pragma unroll
                    for (int j = 0; j < 4; ++j) {
                        int k = j * 64 + L;
                        sh_hold[w][(g * 2 + (j >> 1)) * A2 + (k & 127)] = hv[g * 4 + j];
                    }
            } else {
                #pragma unroll
                for (int g = 0; g < 2; ++g)
                    #pragma unroll
                    for (int j = 0; j < 4; ++j) {
                        int k = j * 64 + L;
                        sh_hold[w][(g * 2 + (j >> 1)) * A2 + (k & 127)] = holdv[g * 4 + j];
                    }
            }

            {   // W1 GEMM: 16 ch x 2 g, 2-lane k-split, 1 shuffle
                const int out = L >> 1, c = out & 15, g = out >> 4, half = L & 1;
                const float* wr = &sh_w[(96 + c) * WST + half * 128];
                const float* ar = &sh_act[w][(g * 2 + half) * A2];
                float acc = 0.f;
                #pragma unroll 16
                for (int kk = 0; kk < 128; ++kk) acc += wr[kk] * ar[kk];
                acc += __shfl_xor(acc, 1, 64);
                if (half == 0) {
                    float v = acc + sh_b1[c];
                    st_tag(xz, (g0 + g) * CDIM + cbase + c, v > 0.f ? v : 0.f, tg);
                }
            }
            for (int e = L; e < K; e += 64) {    // edge filter for this wave's 2 graphs
                size_t off = (size_t)s * K + e;
                if (mskA[off] != 0.f) {
                    int g = gidA[off] - g0;
                    if ((unsigned)g < 2u) {
                        int p = atomicAdd(&sh_cnt[w][g], 1);
                        if (p < CAP) sh_list[w][g][p] = srcA[off] & 63;
                    }
                }
            }

            // ======= P2: poll z; ring = relu(W2 z); aggregate -> agg tagged =======
            float zv[8];
            poll_w(xz, tg, b0, b1, L, zv);
            #pragma unroll
            for (int g = 0; g < 2; ++g)
                #pragma unroll
                for (int j = 0; j < 4; ++j) {
                    int k = j * 64 + L;
                    sh_act[w][(g * 2 + (j >> 1)) * A2 + (k & 127)] = zv[g * 4 + j];
                }
            {   // W2 GEMM -> ring[prev & 63] (wave-private rows, L1-cached)
                const int out = L >> 1, c = out & 15, g = out >> 4, half = L & 1;
                const float* wr = &sh_w[(112 + c) * WST + half * 128];
                const float* ar = &sh_act[w][(g * 2 + half) * A2];
                float acc = 0.f;
                #pragma unroll 16
                for (int kk = 0; kk < 128; ++kk) acc += wr[kk] * ar[kk];
                acc += __shfl_xor(acc, 1, 64);
                if (half == 0) {
                    float v = acc + sh_b2[c];
                    v = v > 0.f ? v : 0.f;
                    ring_blk[((prev & 63) * GW + (2 * w + g)) * CW + c] = v;
                }
            }
            if (L < 32) {
                int g = L >> 4, c = L & 15;
                int n = sh_cnt[w][g]; if (n > CAP) n = CAP;
                float a = 0.f;
                for (int i = 0; i < n; ++i)
                    a += ring_blk[(sh_list[w][g][i] * GW + (2 * w + g)) * CW + c];
                st_tag(xa, (g0 + g) * CDIM + cbase + c, a, tg);
            }

            // ======= P3: gh GEMM (covers agg flight); poll agg; gi GEMM; gates =======
            #pragma unroll
            for (int r = 0; r < 3; ++r) {        // gh: rows 48..95, 3 rounds
                const int out = L >> 1, c = out & 15, g = out >> 4, half = L & 1;
                const int rr = r * 16 + c;
                const float* wr = &sh_w[(48 + rr) * WST + half * 128];
                const float* hr = &sh_hold[w][(g * 2 + half) * A2];
                float acc = 0.f;
                #pragma unroll 16
                for (int kk = 0; kk < 128; ++kk) acc += wr[kk] * hr[kk];
                acc += __shfl_xor(acc, 1, 64);
                if (half == 0) sh_gh[w][g][rr] = acc + sh_bhh[rr];
            }
            float av[8];
            poll_w(xa, tg, b0, b1, L, av);
            #pragma unroll
            for (int g = 0; g < 2; ++g)
                #pragma unroll
                for (int j = 0; j < 4; ++j) {
                    int k = j * 64 + L;
                    sh_act[w][(g * 2 + (j >> 1)) * A2 + (k & 127)] = av[g * 4 + j];
                }
            #pragma unroll
            for (int r = 0; r < 3; ++r) {        // gi: rows 0..47, 3 rounds
                const int out = L >> 1, c = out & 15, g = out >> 4, half = L & 1;
                const int rr = r * 16 + c;
                const float* wr = &sh_w[rr * WST + half * 128];
                const float* ar = &sh_act[w][(g * 2 + half) * A2];
                float acc = 0.f;
                #pragma unroll 16
                for (int kk = 0; kk < 128; ++kk) acc += wr[kk] * ar[kk];
                acc += __shfl_xor(acc, 1, 64);
                if (half == 0) sh_gi[w][g][rr] = acc + sh_bih[rr];
            }
            if (L < 32) {
                int g = L >> 4, c = L & 15;
                float ir = sh_gi[w][g][c], iz = sh_gi[w][g][16 + c], in_ = sh_gi[w][g][32 + c];
                float hr = sh_gh[w][g][c], hz = sh_gh[w][g][16 + c], hn  = sh_gh[w][g][32 + c];
                int k = cbase + c;
                float hold = sh_hold[w][(g * 2 + (k >> 7)) * A2 + (k & 127)];
                float rg = 1.f / (1.f + expf(-(ir + hr)));
                float zg = 1.f / (1.f + expf(-(iz + hz)));
                float nn = tanhf(in_ + rg * hn);
                keep = (1.f - zg) * nn + zg * hold;
                // pass0->pass1 hx handoff: drain this wave's hx stores before the
                // tag that releases chain members into pass 1.
                if (pass == 0 && s == NPER - 1)
                    asm volatile("s_waitcnt vmcnt(0)" ::: "memory");
                st_tag(xh, (g0 + g) * CDIM + cbase + c, keep, tg);
            }
        }
    }
    if (L < 32) {
        int g = L >> 4, c = L & 15;
        st_sc(&hx[((size_t)(g0 + g) * NPER + 0) * CDIM + cbase + c], keep);
    }
}

// ---------------- fallback (round-1 structure, known-correct) ----------------
__global__ __launch_bounds__(512)
void gnn_fallback(const float* __restrict__ x,
                  const float* __restrict__ W1, const float* __restrict__ b1,
                  const float* __restrict__ W2, const float* __restrict__ b2,
                  const float* __restrict__ w_ih, const float* __restrict__ b_ih,
                  const float* __restrict__ w_hh, const float* __restrict__ b_hh,
                  const int* __restrict__ src_f, const int* __restrict__ gid_f,
                  const float* __restrict__ msk_f,
                  const int* __restrict__ src_b, const int* __restrict__ gid_b,
                  const float* __restrict__ msk_b,
                  int Kf, int Kb, float* __restrict__ hx)
{
    const int b = blockIdx.x, t = threadIdx.x;
    __shared__ float sh_ring[64 * CDIM];
    __shared__ float sh_agg[CDIM], sh_hold[CDIM], sh_hnew[CDIM], sh_h1[CDIM];
    __shared__ float sh_gi[3 * CDIM], sh_gh[3 * CDIM];
    __shared__ int   sh_list[256];
    __shared__ int   sh_cnt;
    const size_t base = (size_t)b * NPER * CDIM;
    {
        const float4* x4 = (const float4*)(x + base);
        float4* h4 = (float4*)(hx + base);
        for (int i = t; i < NPER * CDIM / 4; i += 512) h4[i] = x4[i];
    }
    if (t == 0) sh_cnt = 0;
    __syncthreads();
    for (int pass = 0; pass < 2; ++pass) {
        const int* srcA = pass ? src_b : src_f;
        const int* gidA = pass ? gid_b : gid_f;
        const float* mskA = pass ? msk_b : msk_f;
        const int K = pass ? Kb : Kf;
        for (int step = 0; step < NPER; ++step) {
            const int node = pass ? (NPER - 1 - step) : step;
            if (t < CDIM / 4)
                ((float4*)sh_hold)[t] = ((const float4*)(hx + base + (size_t)node * CDIM))[t];
            for (int k = t; k < K; k += 512) {
                size_t off = (size_t)step * K + k;
                if (mskA[off] != 0.f && gidA[off] == b) {
                    int p = atomicAdd(&sh_cnt, 1);
                    if (p < 256) sh_list[p] = srcA[off] & 63;
                }
            }
            __syncthreads();
            int cnt = sh_cnt; if (cnt > 256) cnt = 256;
            if (t < CDIM) {
                float a = 0.f;
                for (int e = 0; e < cnt; ++e) a += sh_ring[sh_list[e] * CDIM + t];
                sh_agg[t] = a;
            }
            __syncthreads();
            #pragma unroll
            for (int d = 0; d < 3; ++d) {
                const int idx = t + d * 512;
                const float *wrow, *inv; float bias; float* outp;
                if (idx < 3 * CDIM) { wrow = w_ih + (size_t)idx * CDIM; inv = sh_agg; bias = b_ih[idx]; outp = &sh_gi[idx]; }
                else { int r = idx - 3 * CDIM; wrow = w_hh + (size_t)r * CDIM; inv = sh_hold; bias = b_hh[r]; outp = &sh_gh[r]; }
                float acc = 0.f;
                const float4* w4 = (const float4*)wrow; const float4* i4 = (const float4*)inv;
                #pragma unroll 8
                for (int j = 0; j < CDIM / 4; ++j) {
                    float4 w = w4[j], v = i4[j];
                    acc += w.x * v.x + w.y * v.y + w.z * v.z + w.w * v.w;
                }
                *outp = acc + bias;
            }
            __syncthreads();
            if (t < CDIM) {
                float ir = sh_gi[t], iz = sh_gi[t + CDIM], in_ = sh_gi[t + 2 * CDIM];
                float hr = sh_gh[t], hz = sh_gh[t + CDIM], hn = sh_gh[t + 2 * CDIM];
                float r = 1.f / (1.f + expf(-(ir + hr)));
                float z = 1.f / (1.f + expf(-(iz + hz)));
                float n = tanhf(in_ + r * hn);
                float hv = (1.f - z) * n + z * sh_hold[t];
                sh_hnew[t] = hv;
                hx[base + (size_t)node * CDIM + t] = hv;
            }
            if (t == 511) sh_cnt = 0;
            __syncthreads();
            if (t < CDIM) {
                const float4* w4 = (const float4*)(W1 + (size_t)t * CDIM);
                const float4* i4 = (const float4*)sh_hnew;
                float acc = 0.f;
                #pragma unroll 8
                for (int j = 0; j < CDIM / 4; ++j) {
                    float4 w = w4[j], v = i4[j];
                    acc += w.x * v.x + w.y * v.y + w.z * v.z + w.w * v.w;
                }
                acc += b1[t];
                sh_h1[t] = acc > 0.f ? acc : 0.f;
            }
            __syncthreads();
            if (t < CDIM) {
                const float4* w4 = (const float4*)(W2 + (size_t)t * CDIM);
                const float4* i4 = (const float4*)sh_h1;
                float acc = 0.f;
                #pragma unroll 8
                for (int j = 0; j < CDIM / 4; ++j) {
                    float4 w = w4[j], v = i4[j];
                    acc += w.x * v.x + w.y * v.y + w.z * v.z + w.w * v.w;
                }
                acc += b2[t];
                sh_ring[(node & 63) * CDIM + t] = acc > 0.f ? acc : 0.f;
            }
            __syncthreads();
        }
    }
}

extern "C" void kernel_launch(void* const* d_in, const int* in_sizes, int n_in,
                              void* d_out, int out_size, void* d_ws, size_t ws_size,
                              hipStream_t stream) {
    const float* x    = (const float*)d_in[0];
    const float* W1   = (const float*)d_in[1];
    const float* b1   = (const float*)d_in[2];
    const float* W2   = (const float*)d_in[3];
    const float* b2   = (const float*)d_in[4];
    const float* w_ih = (const float*)d_in[5];
    const float* b_ih = (const float*)d_in[6];
    const float* w_hh = (const float*)d_in[7];
    const float* b_hh = (const float*)d_in[8];
    const int*   src_f = (const int*)d_in[9];
    const int*   gid_f = (const int*)d_in[10];
    const float* msk_f = (const float*)d_in[11];
    const int*   src_b = (const int*)d_in[12];
    const int*   gid_b = (const int*)d_in[13];
    const float* msk_b = (const float*)d_in[14];

    const int Kf = in_sizes[9]  / NPER;
    const int Kb = in_sizes[12] / NPER;
    float* hx = (float*)d_out;

    char* ws = (char*)d_ws;
    // 4096 pad + 3 tagged exchange buffers (64 graphs x 256 ch x 8B) + ring
    const size_t need = 4096 + 3 * (size_t)BG * CDIM * 8 + (size_t)NB * 64 * GW * CW * 4;
    if (ws_size >= need) {
        float* xh   = (float*)(ws + 4096);
        float* xz   = xh + (size_t)BG * CDIM * 2;
        float* xa   = xz + (size_t)BG * CDIM * 2;
        float* ring = xa + (size_t)BG * CDIM * 2;
        // 3 * 64 * 256 = 49152 u64 pairs to zero; 192 * 256 threads covers exactly.
        init_ws<<<192, 256, 0, stream>>>((unsigned long long*)(ws + 4096), 3 * BG * CDIM);
        gnn_fp32<<<NB, TPB, 0, stream>>>(
            x, W1, b1, W2, b2, w_ih, b_ih, w_hh, b_hh,
            src_f, gid_f, msk_f, src_b, gid_b, msk_b,
            Kf, Kb, hx, xh, xz, xa, ring);
    } else {
        gnn_fallback<<<BG, 512, 0, stream>>>(
            x, W1, b1, W2, b2, w_ih, b_ih, w_hh, b_hh,
            src_f, gid_f, msk_f, src_b, gid_b, msk_b,
            Kf, Kb, hx);
    }
}

// Round 8
// 10162.485 us; speedup vs baseline: 11.3144x; 1.7899x over previous
//
#include <hip/hip_runtime.h>

#define NPER 512
#define CDIM 256
#define BG   64
#define NB   256
#define TPB  256
#define GW   4      // graphs per cluster (16 clusters x 16 member blocks)
#define CW   16     // channels per member block
#define WST  258    // col-major weight stride (256 + 2): bank stride 2 -> free
#define AST  10     // k-major activation stride (4 graphs + pad; stride 10 -> 2-way max)
#define CAP  64

// Zero the tagged exchange buffers (tags must be 0 so step-1 polls for tag 0
// succeed immediately, and stale tags from a previous replay can't alias).
__global__ void init_ws(unsigned long long* p, int n) {
    int i = blockIdx.x * blockDim.x + threadIdx.x;
    if (i < n) p[i] = 0ULL;
}

__device__ __forceinline__ float ld_sc(const float* p) {
    return __hip_atomic_load((const float*)p, __ATOMIC_RELAXED, __HIP_MEMORY_SCOPE_AGENT);
}
__device__ __forceinline__ void st_sc(float* p, float v) {
    __hip_atomic_store(p, v, __ATOMIC_RELAXED, __HIP_MEMORY_SCOPE_AGENT);
}
// One 8B atomic store carries (value, tag) together: no fence / store-order
// assumption anywhere. Agent scope (LLC-homed) -- the proven r1 transport;
// all faster-cache variants were falsified in r2-r4.
__device__ __forceinline__ void st_tag(float* buf, int idx, float v, unsigned tg) {
    unsigned long long u = ((unsigned long long)tg << 32) |
                           (unsigned long long)__float_as_uint(v);
    __hip_atomic_store((unsigned long long*)(buf + 2 * (size_t)idx), u,
                       __ATOMIC_RELAXED, __HIP_MEMORY_SCOPE_AGENT);
}

// Per-wave spin poll: thread tid polls its GW pairs (g*CDIM + tid); each wave
// spins independently on __all (no block barrier per retry). CALLER must issue
// __syncthreads() after return before touching shared staging: that single
// barrier both joins the waves and guarantees the previous phase's LDS readers
// are done (the r1 ordering discipline with fewer barrier rounds).
// Single-buffer WAR safety: unchanged r1 argument -- the step chain
// (hnew->z->agg->hnew) means a producer writing step t has observed all
// step-t inputs, so every consumer finished its step t-1 reads.
__device__ __forceinline__ void poll_tag(const float* buf, unsigned tg, int tid,
                                         float* vals) {
    unsigned long long u[GW];
    int ok = 0;
    do {
        if (!ok) {
            #pragma unroll
            for (int g = 0; g < GW; ++g)
                u[g] = __hip_atomic_load(
                    (const unsigned long long*)(buf + 2 * (size_t)(g * CDIM + tid)),
                    __ATOMIC_RELAXED, __HIP_MEMORY_SCOPE_AGENT);
            ok = 1;
            #pragma unroll
            for (int g = 0; g < GW; ++g) ok &= ((unsigned)(u[g] >> 32) == tg);
        }
    } while (!__all(ok));
    #pragma unroll
    for (int g = 0; g < GW; ++g) vals[g] = __uint_as_float((unsigned)(u[g] & 0xffffffffu));
}

__global__ __launch_bounds__(TPB, 1)
void gnn_fp32(const float* __restrict__ x,
              const float* __restrict__ W1g, const float* __restrict__ b1g,
              const float* __restrict__ W2g, const float* __restrict__ b2g,
              const float* __restrict__ wihg, const float* __restrict__ bihg,
              const float* __restrict__ whhg, const float* __restrict__ bhhg,
              const int* __restrict__ src_f, const int* __restrict__ gid_f,
              const float* __restrict__ msk_f,
              const int* __restrict__ src_b, const int* __restrict__ gid_b,
              const float* __restrict__ msk_b,
              int Kf, int Kb,
              float* __restrict__ hx,
              float* __restrict__ xh, float* __restrict__ xz,
              float* __restrict__ xa, float* __restrict__ ring)
{
    __shared__ float sh_w[128 * WST];    // col-major rows: 0-47 wih, 48-95 whh, 96-111 W1, 112-127 W2
    __shared__ float sh_act[256 * AST];
    __shared__ float sh_hold[256 * AST];
    __shared__ float sh_gi[GW * 48];
    __shared__ float sh_gh[GW * 48];
    __shared__ int   sh_list[GW * CAP];
    __shared__ int   sh_cnt[GW];
    __shared__ float sh_bih[48], sh_bhh[48], sh_b1[CW], sh_b2[CW];

    const int tid   = threadIdx.x;
    const int cl    = blockIdx.x & 15;   // 16 clusters
    const int mb    = blockIdx.x >> 4;   // 16 member blocks per cluster
    const int gb    = cl * GW;
    const int cbase = mb * CW;

    float* xh_c = xh + (size_t)cl * GW * CDIM * 2;
    float* xz_c = xz + (size_t)cl * GW * CDIM * 2;
    float* xa_c = xa + (size_t)cl * GW * CDIM * 2;
    float* ring_blk = ring + (size_t)blockIdx.x * 64 * GW * CW;

    // ---- stage weights col-major into LDS, once ----
    for (int e = tid; e < 128 * 256; e += TPB) {
        int r = e >> 8, k = e & 255;
        const float* sp; int grow;
        if (r < 48)       { sp = wihg; grow = (r >> 4) * CDIM + cbase + (r & 15); }
        else if (r < 96)  { sp = whhg; grow = ((r - 48) >> 4) * CDIM + cbase + ((r - 48) & 15); }
        else if (r < 112) { sp = W1g;  grow = cbase + (r - 96); }
        else              { sp = W2g;  grow = cbase + (r - 112); }
        sh_w[r * WST + k] = sp[(size_t)grow * CDIM + k];
    }
    if (tid < 48) {
        sh_bih[tid] = bihg[(tid >> 4) * CDIM + cbase + (tid & 15)];
        sh_bhh[tid] = bhhg[(tid >> 4) * CDIM + cbase + (tid & 15)];
    } else if (tid < 64) {
        sh_b1[tid - 48] = b1g[cbase + tid - 48];
        sh_b2[tid - 48] = b2g[cbase + tid - 48];
    }
    __syncthreads();

    float keep0 = 0.f;
    const int cg = tid >> 4;     // for tid<64: local graph 0..3
    const int cc = tid & 15;     // channel within block's 16

    for (int pass = 0; pass < 2; ++pass) {
        const int* srcA   = pass ? src_b : src_f;
        const int* gidA   = pass ? gid_b : gid_f;
        const float* mskA = pass ? msk_b : msk_f;
        const int K = pass ? Kb : Kf;

        for (int s = 0; s < NPER; ++s) {
            const int node = pass ? (NPER - 1 - s) : s;
            const unsigned tg = (unsigned)(pass * NPER + s + 1);
            const bool has_prev = !(pass == 0 && s == 0);
            const int prev = (s > 0) ? (pass ? node + 1 : node - 1) : (NPER - 1);

            // ======= P1: deferred hx write; hold prefetch; poll hnew; W1 GEMM =======
            if (has_prev && tid < 64)
                st_sc(&hx[((size_t)(gb + cg) * NPER + prev) * CDIM + cbase + cc], keep0);
            float holdv[GW];
            if (pass == 1 && s > 0) {           // issue early: completes under the poll
                #pragma unroll
                for (int j = 0; j < GW; ++j)
                    holdv[j] = ld_sc(&hx[((size_t)(gb + j) * NPER + node) * CDIM + tid]);
            }
            if (tid < GW) sh_cnt[tid] = 0;

            float hv[GW];
            poll_tag(xh_c, tg - 1, tid, hv);    // tag 0 at (pass0,s0): zeros, unused downstream
            __syncthreads();                    // join waves; prev-phase LDS readers done
            #pragma unroll
            for (int j = 0; j < GW; ++j) sh_act[tid * AST + j] = hv[j];
            if (pass == 0) {                    // h_old = x (read-only: cached loads)
                int sg = tid & 3, kb = (tid >> 2) << 2;
                const float* op = x + ((size_t)(gb + sg) * NPER + node) * CDIM + kb;
                float4 h0 = *(const float4*)op;
                float* d = &sh_hold[kb * AST + sg];
                d[0] = h0.x; d[AST] = h0.y; d[2 * AST] = h0.z; d[3 * AST] = h0.w;
            } else if (s == 0) {                // h_old(node 511) == hnew from fwd end
                #pragma unroll
                for (int j = 0; j < GW; ++j) sh_hold[tid * AST + j] = hv[j];
            } else {
                #pragma unroll
                for (int j = 0; j < GW; ++j) sh_hold[tid * AST + j] = holdv[j];
            }
            __syncthreads();

            {   // W1 GEMM (rows 96..111) -> z tagged
                const int tl = tid >> 5, ks = tid & 31;
                const float* wr0 = &sh_w[(96 + tl * 2) * WST];
                const float* wr1 = wr0 + WST;
                float acc0[GW] = {}, acc1[GW] = {};
                #pragma unroll
                for (int j = 0; j < 8; ++j) {
                    int k = ks + j * 32;
                    float w0 = wr0[k], w1 = wr1[k];
                    const float* ap = &sh_act[k * AST];
                    #pragma unroll
                    for (int g = 0; g < GW; ++g) {
                        float a = ap[g];
                        acc0[g] += w0 * a; acc1[g] += w1 * a;
                    }
                }
                #pragma unroll
                for (int m = 1; m < 32; m <<= 1)
                    #pragma unroll
                    for (int g = 0; g < GW; ++g) {
                        acc0[g] += __shfl_xor(acc0[g], m, 64);
                        acc1[g] += __shfl_xor(acc1[g], m, 64);
                    }
                if (ks < GW) {
                    int g = ks, c0 = tl * 2;
                    float v0 = acc0[g] + sh_b1[c0];
                    float v1 = acc1[g] + sh_b1[c0 + 1];
                    st_tag(xz_c, g * CDIM + cbase + c0,     v0 > 0.f ? v0 : 0.f, tg);
                    st_tag(xz_c, g * CDIM + cbase + c0 + 1, v1 > 0.f ? v1 : 0.f, tg);
                }
            }
            // edge filter here: covers z's flight to the LLC before the P2 poll
            for (int e = tid; e < K; e += TPB) {
                size_t off = (size_t)s * K + e;
                if (mskA[off] != 0.f) {
                    int g = gidA[off] - gb;
                    if ((unsigned)g < GW) {
                        int p = atomicAdd(&sh_cnt[g], 1);
                        if (p < CAP) sh_list[g * CAP + p] = srcA[off] & 63;
                    }
                }
            }

            // ======= P2: poll z; ring = relu(W2 z); aggregate -> agg tagged =======
            float zv[GW];
            poll_tag(xz_c, tg, tid, zv);
            __syncthreads();
            #pragma unroll
            for (int j = 0; j < GW; ++j) sh_act[tid * AST + j] = zv[j];
            __syncthreads();

            {   // W2 GEMM (rows 112..127) -> ring[prev & 63] (block-private, cached)
                const int tl = tid >> 5, ks = tid & 31;
                const float* wr0 = &sh_w[(112 + tl * 2) * WST];
                const float* wr1 = wr0 + WST;
                float acc0[GW] = {}, acc1[GW] = {};
                #pragma unroll
                for (int j = 0; j < 8; ++j) {
                    int k = ks + j * 32;
                    float w0 = wr0[k], w1 = wr1[k];
                    const float* ap = &sh_act[k * AST];
                    #pragma unroll
                    for (int g = 0; g < GW; ++g) {
                        float a = ap[g];
                        acc0[g] += w0 * a; acc1[g] += w1 * a;
                    }
                }
                #pragma unroll
                for (int m = 1; m < 32; m <<= 1)
                    #pragma unroll
                    for (int g = 0; g < GW; ++g) {
                        acc0[g] += __shfl_xor(acc0[g], m, 64);
                        acc1[g] += __shfl_xor(acc1[g], m, 64);
                    }
                if (ks < GW) {
                    int g = ks, c0 = tl * 2, slot = prev & 63;
                    float v0 = acc0[g] + sh_b2[c0];
                    float v1 = acc1[g] + sh_b2[c0 + 1];
                    ring_blk[(slot * GW + g) * CW + c0]     = v0 > 0.f ? v0 : 0.f;
                    ring_blk[(slot * GW + g) * CW + c0 + 1] = v1 > 0.f ? v1 : 0.f;
                }
            }
            __syncthreads();
            if (tid < 64) {
                int n = sh_cnt[cg]; if (n > CAP) n = CAP;
                float a = 0.f;
                for (int i = 0; i < n; ++i)
                    a += ring_blk[(sh_list[cg * CAP + i] * GW + cg) * CW + cc];
                st_tag(xa_c, cg * CDIM + cbase + cc, a, tg);
            }

            // ======= P3: gh GEMM (covers agg flight); poll agg; gi GEMM; gates =======
            if (tid < 192) {  // gh GEMM (rows 48..95) -> sh_gh
                const int tl = tid >> 4, ks = tid & 15;
                const float* wr = &sh_w[(48 + tl * 4) * WST];
                float acc[4][GW] = {};
                #pragma unroll 4
                for (int j = 0; j < 16; ++j) {
                    int k = ks + j * 16;
                    float w0 = wr[k], w1 = wr[WST + k], w2 = wr[2 * WST + k], w3 = wr[3 * WST + k];
                    const float* ap = &sh_hold[k * AST];
                    #pragma unroll
                    for (int g = 0; g < GW; ++g) {
                        float a = ap[g];
                        acc[0][g] += w0 * a; acc[1][g] += w1 * a;
                        acc[2][g] += w2 * a; acc[3][g] += w3 * a;
                    }
                }
                #pragma unroll
                for (int m = 1; m < 16; m <<= 1)
                    #pragma unroll
                    for (int r = 0; r < 4; ++r)
                        #pragma unroll
                        for (int g = 0; g < GW; ++g)
                            acc[r][g] += __shfl_xor(acc[r][g], m, 64);
                if (ks < GW) {
                    int g = ks;
                    #pragma unroll
                    for (int r = 0; r < 4; ++r)
                        sh_gh[g * 48 + tl * 4 + r] = acc[r][g] + sh_bhh[tl * 4 + r];
                }
            }
            float av[GW];
            poll_tag(xa_c, tg, tid, av);
            __syncthreads();
            #pragma unroll
            for (int j = 0; j < GW; ++j) sh_act[tid * AST + j] = av[j];
            __syncthreads();
            if (tid < 192) {  // gi GEMM (rows 0..47) -> sh_gi
                const int tl = tid >> 4, ks = tid & 15;
                const float* wr = &sh_w[(tl * 4) * WST];
                float acc[4][GW] = {};
                #pragma unroll 4
                for (int j = 0; j < 16; ++j) {
                    int k = ks + j * 16;
                    float w0 = wr[k], w1 = wr[WST + k], w2 = wr[2 * WST + k], w3 = wr[3 * WST + k];
                    const float* ap = &sh_act[k * AST];
                    #pragma unroll
                    for (int g = 0; g < GW; ++g) {
                        float a = ap[g];
                        acc[0][g] += w0 * a; acc[1][g] += w1 * a;
                        acc[2][g] += w2 * a; acc[3][g] += w3 * a;
                    }
                }
                #pragma unroll
                for (int m = 1; m < 16; m <<= 1)
                    #pragma unroll
                    for (int r = 0; r < 4; ++r)
                        #pragma unroll
                        for (int g = 0; g < GW; ++g)
                            acc[r][g] += __shfl_xor(acc[r][g], m, 64);
                if (ks < GW) {
                    int g = ks;
                    #pragma unroll
                    for (int r = 0; r < 4; ++r)
                        sh_gi[g * 48 + tl * 4 + r] = acc[r][g] + sh_bih[tl * 4 + r];
                }
            }
            __syncthreads();
            if (tid < 64) {
                float ir = sh_gi[cg * 48 + cc], iz = sh_gi[cg * 48 + 16 + cc], in_ = sh_gi[cg * 48 + 32 + cc];
                float hr = sh_gh[cg * 48 + cc], hz = sh_gh[cg * 48 + 16 + cc], hn  = sh_gh[cg * 48 + 32 + cc];
                float hold = sh_hold[(cbase + cc) * AST + cg];
                float r  = 1.f / (1.f + expf(-(ir + hr)));
                float z_ = 1.f / (1.f + expf(-(iz + hz)));
                float nn = tanhf(in_ + r * hn);
                keep0 = (1.f - z_) * nn + z_ * hold;
                // pass0->pass1 hx handoff: drain this thread's hx stores before
                // the tag that releases other blocks into pass 1.
                if (pass == 0 && s == NPER - 1)
                    asm volatile("s_waitcnt vmcnt(0)" ::: "memory");
                st_tag(xh_c, cg * CDIM + cbase + cc, keep0, tg);
            }
        }
    }
    if (tid < 64)
        st_sc(&hx[((size_t)(gb + cg) * NPER + 0) * CDIM + cbase + cc], keep0);
}

// ---------------- fallback (round-1 structure, known-correct) ----------------
__global__ __launch_bounds__(512)
void gnn_fallback(const float* __restrict__ x,
                  const float* __restrict__ W1, const float* __restrict__ b1,
                  const float* __restrict__ W2, const float* __restrict__ b2,
                  const float* __restrict__ w_ih, const float* __restrict__ b_ih,
                  const float* __restrict__ w_hh, const float* __restrict__ b_hh,
                  const int* __restrict__ src_f, const int* __restrict__ gid_f,
                  const float* __restrict__ msk_f,
                  const int* __restrict__ src_b, const int* __restrict__ gid_b,
                  const float* __restrict__ msk_b,
                  int Kf, int Kb, float* __restrict__ hx)
{
    const int b = blockIdx.x, t = threadIdx.x;
    __shared__ float sh_ring[64 * CDIM];
    __shared__ float sh_agg[CDIM], sh_hold[CDIM], sh_hnew[CDIM], sh_h1[CDIM];
    __shared__ float sh_gi[3 * CDIM], sh_gh[3 * CDIM];
    __shared__ int   sh_list[256];
    __shared__ int   sh_cnt;
    const size_t base = (size_t)b * NPER * CDIM;
    {
        const float4* x4 = (const float4*)(x + base);
        float4* h4 = (float4*)(hx + base);
        for (int i = t; i < NPER * CDIM / 4; i += 512) h4[i] = x4[i];
    }
    if (t == 0) sh_cnt = 0;
    __syncthreads();
    for (int pass = 0; pass < 2; ++pass) {
        const int* srcA = pass ? src_b : src_f;
        const int* gidA = pass ? gid_b : gid_f;
        const float* mskA = pass ? msk_b : msk_f;
        const int K = pass ? Kb : Kf;
        for (int step = 0; step < NPER; ++step) {
            const int node = pass ? (NPER - 1 - step) : step;
            if (t < CDIM / 4)
                ((float4*)sh_hold)[t] = ((const float4*)(hx + base + (size_t)node * CDIM))[t];
            for (int k = t; k < K; k += 512) {
                size_t off = (size_t)step * K + k;
                if (mskA[off] != 0.f && gidA[off] == b) {
                    int p = atomicAdd(&sh_cnt, 1);
                    if (p < 256) sh_list[p] = srcA[off] & 63;
                }
            }
            __syncthreads();
            int cnt = sh_cnt; if (cnt > 256) cnt = 256;
            if (t < CDIM) {
                float a = 0.f;
                for (int e = 0; e < cnt; ++e) a += sh_ring[sh_list[e] * CDIM + t];
                sh_agg[t] = a;
            }
            __syncthreads();
            #pragma unroll
            for (int d = 0; d < 3; ++d) {
                const int idx = t + d * 512;
                const float *wrow, *inv; float bias; float* outp;
                if (idx < 3 * CDIM) { wrow = w_ih + (size_t)idx * CDIM; inv = sh_agg; bias = b_ih[idx]; outp = &sh_gi[idx]; }
                else { int r = idx - 3 * CDIM; wrow = w_hh + (size_t)r * CDIM; inv = sh_hold; bias = b_hh[r]; outp = &sh_gh[r]; }
                float acc = 0.f;
                const float4* w4 = (const float4*)wrow; const float4* i4 = (const float4*)inv;
                #pragma unroll 8
                for (int j = 0; j < CDIM / 4; ++j) {
                    float4 w = w4[j], v = i4[j];
                    acc += w.x * v.x + w.y * v.y + w.z * v.z + w.w * v.w;
                }
                *outp = acc + bias;
            }
            __syncthreads();
            if (t < CDIM) {
                float ir = sh_gi[t], iz = sh_gi[t + CDIM], in_ = sh_gi[t + 2 * CDIM];
                float hr = sh_gh[t], hz = sh_gh[t + CDIM], hn = sh_gh[t + 2 * CDIM];
                float r = 1.f / (1.f + expf(-(ir + hr)));
                float z = 1.f / (1.f + expf(-(iz + hz)));
                float n = tanhf(in_ + r * hn);
                float hv = (1.f - z) * n + z * sh_hold[t];
                sh_hnew[t] = hv;
                hx[base + (size_t)node * CDIM + t] = hv;
            }
            if (t == 511) sh_cnt = 0;
            __syncthreads();
            if (t < CDIM) {
                const float4* w4 = (const float4*)(W1 + (size_t)t * CDIM);
                const float4* i4 = (const float4*)sh_hnew;
                float acc = 0.f;
                #pragma unroll 8
                for (int j = 0; j < CDIM / 4; ++j) {
                    float4 w = w4[j], v = i4[j];
                    acc += w.x * v.x + w.y * v.y + w.z * v.z + w.w * v.w;
                }
                acc += b1[t];
                sh_h1[t] = acc > 0.f ? acc : 0.f;
            }
            __syncthreads();
            if (t < CDIM) {
                const float4* w4 = (const float4*)(W2 + (size_t)t * CDIM);
                const float4* i4 = (const float4*)sh_h1;
                float acc = 0.f;
                #pragma unroll 8
                for (int j = 0; j < CDIM / 4; ++j) {
                    float4 w = w4[j], v = i4[j];
                    acc += w.x * v.x + w.y * v.y + w.z * v.z + w.w * v.w;
                }
                acc += b2[t];
                sh_ring[(node & 63) * CDIM + t] = acc > 0.f ? acc : 0.f;
            }
            __syncthreads();
        }
    }
}

extern "C" void kernel_launch(void* const* d_in, const int* in_sizes, int n_in,
                              void* d_out, int out_size, void* d_ws, size_t ws_size,
                              hipStream_t stream) {
    const float* x    = (const float*)d_in[0];
    const float* W1   = (const float*)d_in[1];
    const float* b1   = (const float*)d_in[2];
    const float* W2   = (const float*)d_in[3];
    const float* b2   = (const float*)d_in[4];
    const float* w_ih = (const float*)d_in[5];
    const float* b_ih = (const float*)d_in[6];
    const float* w_hh = (const float*)d_in[7];
    const float* b_hh = (const float*)d_in[8];
    const int*   src_f = (const int*)d_in[9];
    const int*   gid_f = (const int*)d_in[10];
    const float* msk_f = (const float*)d_in[11];
    const int*   src_b = (const int*)d_in[12];
    const int*   gid_b = (const int*)d_in[13];
    const float* msk_b = (const float*)d_in[14];

    const int Kf = in_sizes[9]  / NPER;
    const int Kb = in_sizes[12] / NPER;
    float* hx = (float*)d_out;

    char* ws = (char*)d_ws;
    // 4096 pad + 3 tagged exchange buffers (64 graphs x 256 ch x 8B) + ring
    const size_t need = 4096 + 3 * (size_t)BG * CDIM * 8 + (size_t)NB * 64 * GW * CW * 4;
    if (ws_size >= need) {
        float* xh   = (float*)(ws + 4096);
        float* xz   = xh + (size_t)BG * CDIM * 2;
        float* xa   = xz + (size_t)BG * CDIM * 2;
        float* ring = xa + (size_t)BG * CDIM * 2;
        // 3 * 64 * 256 = 49152 u64 pairs to zero; 192 * 256 threads covers exactly.
        init_ws<<<192, 256, 0, stream>>>((unsigned long long*)(ws + 4096), 3 * BG * CDIM);
        gnn_fp32<<<NB, TPB, 0, stream>>>(
            x, W1, b1, W2, b2, w_ih, b_ih, w_hh, b_hh,
            src_f, gid_f, msk_f, src_b, gid_b, msk_b,
            Kf, Kb, hx, xh, xz, xa, ring);
    } else {
        gnn_fallback<<<BG, 512, 0, stream>>>(
            x, W1, b1, W2, b2, w_ih, b_ih, w_hh, b_hh,
            src_f, gid_f, msk_f, src_b, gid_b, msk_b,
            Kf, Kb, hx);
    }
}